// Round 5
// baseline (1209.567 us; speedup 1.0000x reference)
//
#include <hip/hip_runtime.h>
#include <hip/hip_bf16.h>
#include <math.h>

#define HW 102400        // 320*320
#define KSEL 4096
#define CAP 16384

// ---------- helpers ----------
__device__ inline unsigned fkey(float f) {
    unsigned u = __float_as_uint(f);
    return (u & 0x80000000u) ? ~u : (u | 0x80000000u);
}

// wave64 sum via DPP (row_shr 1/2/4/8 + row_bcast 15/31); result valid in lane 63,
// returned through readlane -> SGPR (wave-uniform, enables scalar branch).
__device__ inline unsigned wave_sum64_s(unsigned x) {
    x += (unsigned)__builtin_amdgcn_update_dpp(0, (int)x, 0x111, 0xf, 0xf, false);
    x += (unsigned)__builtin_amdgcn_update_dpp(0, (int)x, 0x112, 0xf, 0xf, false);
    x += (unsigned)__builtin_amdgcn_update_dpp(0, (int)x, 0x114, 0xf, 0xf, false);
    x += (unsigned)__builtin_amdgcn_update_dpp(0, (int)x, 0x118, 0xf, 0xf, false);
    x += (unsigned)__builtin_amdgcn_update_dpp(0, (int)x, 0x142, 0xa, 0xf, false);
    x += (unsigned)__builtin_amdgcn_update_dpp(0, (int)x, 0x143, 0xc, 0xf, false);
    return (unsigned)__builtin_amdgcn_readlane((int)x, 63);
}

// ---------- K1: score + class argmax (+ fused histogram) ----------
// Block = 256 pixels. Channels staged through LDS in 16-channel double-buffered
// tiles; each wave reads 4 x 1KB CONTIGUOUS chunks per tile (no 4KB-multiple
// stride camping). Per-pixel accumulation is the exact sequential c=0..255 fmaf
// chain (bit-stable vs prior rounds, absmax 0.0). Argmax ascending, strictly
// greater => identical first-max-index semantics.
__global__ __launch_bounds__(256) void k_score(const float* __restrict__ x,
                                               const float* __restrict__ sm,
                                               float* __restrict__ score,
                                               int* __restrict__ clsidx,
                                               unsigned* __restrict__ hist) {
    __shared__ float swt[256][16];      // swt[c][k] = sm[k*256+c]
    __shared__ float tile[2][16][256];  // [buf][channel-in-tile][pixel]
    int t = threadIdx.x;
    for (int i = t; i < 4096; i += 256) {
        int k = i >> 8, c = i & 255;
        swt[c][k] = sm[i];              // sm[i] == sm[k*256+c]
    }
    int wave = t >> 6, lane = t & 63;
    size_t pxb = (size_t)blockIdx.x * 256;
    const float* xc = x + (size_t)5 * HW + pxb;   // class-channel base for this block

    float4 st[4];
    // prologue: load tile 0 (channels 0..15)
#pragma unroll
    for (int j = 0; j < 4; ++j)
        st[j] = *(const float4*)(xc + (size_t)(wave * 4 + j) * HW + lane * 4);
#pragma unroll
    for (int j = 0; j < 4; ++j)
        ((float4*)&tile[0][wave * 4 + j][0])[lane] = st[j];
    __syncthreads();

    float acc[16];
#pragma unroll
    for (int k = 0; k < 16; ++k) acc[k] = 0.f;

    for (int ct = 0; ct < 16; ++ct) {
        int buf = ct & 1;
        if (ct + 1 < 16) {
#pragma unroll
            for (int j = 0; j < 4; ++j)
                st[j] = *(const float4*)(xc + (size_t)((ct + 1) * 16 + wave * 4 + j) * HW + lane * 4);
        }
        // compute on tile[buf]: channels ct*16 .. ct*16+15, ascending
#pragma unroll
        for (int cc = 0; cc < 16; ++cc) {
            float xv = tile[buf][cc][t];
            const float4* w4 = (const float4*)&swt[ct * 16 + cc][0];
            float4 w0 = w4[0], w1 = w4[1], w2 = w4[2], w3 = w4[3];
            acc[0]  = fmaf(xv, w0.x, acc[0]);  acc[1]  = fmaf(xv, w0.y, acc[1]);
            acc[2]  = fmaf(xv, w0.z, acc[2]);  acc[3]  = fmaf(xv, w0.w, acc[3]);
            acc[4]  = fmaf(xv, w1.x, acc[4]);  acc[5]  = fmaf(xv, w1.y, acc[5]);
            acc[6]  = fmaf(xv, w1.z, acc[6]);  acc[7]  = fmaf(xv, w1.w, acc[7]);
            acc[8]  = fmaf(xv, w2.x, acc[8]);  acc[9]  = fmaf(xv, w2.y, acc[9]);
            acc[10] = fmaf(xv, w2.z, acc[10]); acc[11] = fmaf(xv, w2.w, acc[11]);
            acc[12] = fmaf(xv, w3.x, acc[12]); acc[13] = fmaf(xv, w3.y, acc[13]);
            acc[14] = fmaf(xv, w3.z, acc[14]); acc[15] = fmaf(xv, w3.w, acc[15]);
        }
        __syncthreads();
        if (ct + 1 < 16) {
#pragma unroll
            for (int j = 0; j < 4; ++j)
                ((float4*)&tile[buf ^ 1][wave * 4 + j][0])[lane] = st[j];
            __syncthreads();
        }
    }

    float mv = acc[0]; int mi = 0;
#pragma unroll
    for (int k = 1; k < 16; ++k)
        if (acc[k] > mv) { mv = acc[k]; mi = k; }
    int n = (int)pxb + t;
    float x0 = x[n];
    float sig = 1.0f / (1.0f + expf(-x0));
    float sc = (sig > 0.5f) ? sig * mv : -INFINITY;
    score[n] = sc;
    clsidx[n] = mi;
    atomicAdd(&hist[fkey(sc) >> 16], 1u);
}

// ---------- K3: find 16-bit prefix p16 such that count(key>>16 >= p16) >= K ----------
__global__ __launch_bounds__(1024) void k_findp(const unsigned* __restrict__ hist,
                                                unsigned* __restrict__ meta) {
    __shared__ unsigned part[1024];
    __shared__ unsigned sgrp, s_after;
    __shared__ unsigned bins[64];
    int t = threadIdx.x;
    if (t == 0) { sgrp = 0; s_after = 0; }
    unsigned s = 0;
    const unsigned* hp = hist + t * 64;
    for (int i = 0; i < 64; ++i) s += hp[i];
    part[t] = s;
    __syncthreads();
    for (int off = 1; off < 1024; off <<= 1) {
        unsigned v = (t + off < 1024) ? part[t + off] : 0u;
        __syncthreads();
        part[t] += v;
        __syncthreads();
    }
    if (part[t] >= KSEL && (t == 1023 || part[t + 1] < KSEL)) {
        sgrp = (unsigned)t;
        s_after = (t == 1023) ? 0u : part[t + 1];
    }
    __syncthreads();
    unsigned g = sgrp, SA = s_after;
    if (t < 64) bins[t] = hist[g * 64 + t];
    __syncthreads();
    if (t == 0) {
        unsigned acc = SA, p = g * 64;
        for (int b = 63; b >= 0; --b) {
            acc += bins[b];
            if (acc >= KSEL) { p = g * 64 + (unsigned)b; break; }
        }
        meta[1] = p;
    }
}

// ---------- K4: collect candidates with key>>16 >= p16 ----------
__global__ void k_collect(const float* __restrict__ score,
                          unsigned* __restrict__ meta,
                          unsigned long long* __restrict__ cand) {
    int n = blockIdx.x * 256 + threadIdx.x;
    unsigned key = fkey(score[n]);
    if ((key >> 16) >= meta[1]) {
        unsigned pos = atomicAdd(&meta[0], 1u);
        if (pos < CAP)
            cand[pos] = ((unsigned long long)key << 32) | (unsigned)(~(unsigned)n);
    }
}

// ---------- K5: rank candidates (exact top-k ordering) + gather ----------
__global__ __launch_bounds__(256) void k_rank(const unsigned long long* __restrict__ cand,
                                              const unsigned* __restrict__ meta,
                                              const float* __restrict__ x,
                                              const float* __restrict__ score,
                                              const int* __restrict__ clsidx,
                                              float* __restrict__ topv,
                                              float* __restrict__ bl, float* __restrict__ bt,
                                              float* __restrict__ br, float* __restrict__ bb,
                                              float* __restrict__ area, int* __restrict__ clsk) {
    __shared__ unsigned long long tile[1024];
    int C = (int)meta[0]; if (C > CAP) C = CAP;
    int j = blockIdx.x * 256 + threadIdx.x;
    unsigned long long kj = (j < C) ? cand[j] : 0ull;
    unsigned rank = 0;
    for (int tb = 0; tb < C; tb += 1024) {
        int cnt = min(1024, C - tb);
        __syncthreads();
        for (int u = threadIdx.x; u < cnt; u += 256) tile[u] = cand[tb + u];
        __syncthreads();
        if (j < C)
            for (int u = 0; u < cnt; ++u) rank += (tile[u] > kj) ? 1u : 0u;
    }
    if (j < C && rank < KSEL) {
        unsigned n = ~(unsigned)(kj & 0xFFFFFFFFull);
        float l  = x[(size_t)1 * HW + n];
        float tt = x[(size_t)2 * HW + n];
        float r  = x[(size_t)3 * HW + n];
        float b  = x[(size_t)4 * HW + n];
        topv[rank] = score[n];
        bl[rank] = l; bt[rank] = tt; br[rank] = r; bb[rank] = b;
        area[rank] = (r - l) * (b - tt);
        clsk[rank] = clsidx[n];
    }
}

// ---------- K6: pairwise IoU >= 0.2 bitmask, ROW-MAJOR mask[i][w] ----------
__global__ __launch_bounds__(256) void k_mask(const float* __restrict__ bl, const float* __restrict__ bt,
                                              const float* __restrict__ br, const float* __restrict__ bb,
                                              const float* __restrict__ area,
                                              unsigned long long* __restrict__ mask) {
    __shared__ float sl[256], st[256], sr[256], sb[256], sa[256];
    int t = threadIdx.x;
    int ic = blockIdx.x >> 4;
    int jc = blockIdx.x & 15;
    int i = ic * 256 + t;
    int j0 = jc * 256;
    sl[t] = bl[j0 + t]; st[t] = bt[j0 + t]; sr[t] = br[j0 + t];
    sb[t] = bb[j0 + t]; sa[t] = area[j0 + t];
    __syncthreads();
    float li = bl[i], ti = bt[i], ri = br[i], bi = bb[i], ai = area[i];
#pragma unroll
    for (int w = 0; w < 4; ++w) {
        unsigned long long m = 0;
        for (int k2 = 0; k2 < 64; ++k2) {
            int j = w * 64 + k2;
            float iw = fminf(ri, sr[j]) - fmaxf(li, sl[j]); iw = fmaxf(iw, 0.f);
            float ih = fminf(bi, sb[j]) - fmaxf(ti, st[j]); ih = fmaxf(ih, 0.f);
            float inter = iw * ih;
            float uni = ai + sa[j] - inter + 1e-10f;
            if (inter / uni >= 0.2f) m |= (1ull << k2);
        }
        mask[(size_t)i * 64 + (jc * 4 + w)] = m;
    }
}

// ---------- K7: sequential greedy scan, 1 wave, NAMED-register ping-pong ----------
__global__ __launch_bounds__(64) void k_nms(const unsigned long long* __restrict__ mask,
                                            const float* __restrict__ topv,
                                            const float* __restrict__ area,
                                            unsigned long long* __restrict__ keptW) {
    int lane = threadIdx.x;
    unsigned long long alive = 0, areaok = 0, kept = 0;
    for (int k = 0; k < 64; ++k) {
        float tv = topv[(size_t)k * 64 + lane];
        float ar = area[(size_t)k * 64 + lane];
        unsigned long long b1 = __ballot(tv != -INFINITY);
        unsigned long long b2 = __ballot(ar >= 4.0f);
        if (lane == k) { alive = b1; areaok = b2; }
    }
    const unsigned long long* mrow = mask + lane;   // mask[i*64 + lane]
    unsigned long long cw = 0, caw = 0;
    unsigned long long a0,a1,a2,a3,a4,a5,a6,a7, b0,b1,b2,b3,b4,b5,b6,b7;

#define LD(v, i) v = mrow[(size_t)(i) * 64]

#define PR(v, i)                                                          \
    {                                                                     \
        int w = (i) >> 6, b = (i) & 63;                                   \
        if (b == 0) { cw = __shfl(alive, w); caw = __shfl(areaok, w); }   \
        unsigned long long bit = 1ull << b;                               \
        if (cw & bit) {                                                   \
            if (lane == w) alive &= ~bit;                                 \
            cw &= ~bit;                                                   \
            unsigned c = __popcll(v & alive);                             \
            unsigned tot = wave_sum64_s(c);                               \
            if (tot >= 10u && (caw & bit)) {                              \
                alive &= ~v;                                              \
                unsigned long long mw = __shfl(v, w);                     \
                cw &= ~mw;                                                \
                if (lane == w) kept |= bit;                               \
            }                                                             \
        }                                                                 \
    }

    LD(a0, 0); LD(a1, 1); LD(a2, 2); LD(a3, 3);
    LD(a4, 4); LD(a5, 5); LD(a6, 6); LD(a7, 7);
    LD(b0, 8); LD(b1, 9); LD(b2, 10); LD(b3, 11);
    LD(b4, 12); LD(b5, 13); LD(b6, 14); LD(b7, 15);
    for (int base = 0; base < 4096; base += 16) {
        PR(a0, base + 0); PR(a1, base + 1); PR(a2, base + 2); PR(a3, base + 3);
        PR(a4, base + 4); PR(a5, base + 5); PR(a6, base + 6); PR(a7, base + 7);
        if (base + 16 < 4096) {
            LD(a0, base + 16); LD(a1, base + 17); LD(a2, base + 18); LD(a3, base + 19);
            LD(a4, base + 20); LD(a5, base + 21); LD(a6, base + 22); LD(a7, base + 23);
        }
        PR(b0, base + 8); PR(b1, base + 9); PR(b2, base + 10); PR(b3, base + 11);
        PR(b4, base + 12); PR(b5, base + 13); PR(b6, base + 14); PR(b7, base + 15);
        if (base + 16 < 4096) {
            LD(b0, base + 24); LD(b1, base + 25); LD(b2, base + 26); LD(b3, base + 27);
            LD(b4, base + 28); LD(b5, base + 29); LD(b6, base + 30); LD(b7, base + 31);
        }
    }
    keptW[lane] = kept;
#undef LD
#undef PR
}

// ---------- K8: epilogue ----------
__global__ __launch_bounds__(256) void k_out(const unsigned long long* __restrict__ keptW,
                                             const float* __restrict__ topv,
                                             const float* __restrict__ bl, const float* __restrict__ bt,
                                             const float* __restrict__ br, const float* __restrict__ bb,
                                             const int* __restrict__ clsk,
                                             const float* __restrict__ padding,
                                             const float* __restrict__ ratio,
                                             const int* __restrict__ piw, const int* __restrict__ pih,
                                             float* __restrict__ out) {
    int i = blockIdx.x * 256 + threadIdx.x;
    if (i >= KSEL) return;
    bool kept = (keptW[i >> 6] >> (i & 63)) & 1ull;
    float tv = topv[i];
    bool keep = kept && (tv >= 0.5f);
    float p0 = padding[0], p1 = padding[1];
    float invr = 1.0f / ratio[0];
    float W_ = (float)piw[0], H_ = (float)pih[0];
    float x1 = fmaxf((bl[i] - p0) * invr, 0.f);
    float y1 = fmaxf((bt[i] - p1) * invr, 0.f);
    float x2 = fminf((br[i] - p0) * invr, W_);
    float y2 = fminf((bb[i] - p1) * invr, H_);
    keep = keep && (x1 < W_) && (y1 < H_);
    float* o = out + (size_t)i * 7;
    if (keep) {
        o[0] = 1.0f; o[1] = tv; o[2] = x1; o[3] = y1; o[4] = x2; o[5] = y2;
        o[6] = (float)clsk[i];
    } else {
        o[0] = 0.f; o[1] = 0.f; o[2] = 0.f; o[3] = 0.f; o[4] = 0.f; o[5] = 0.f; o[6] = 0.f;
    }
}

extern "C" void kernel_launch(void* const* d_in, const int* in_sizes, int n_in,
                              void* d_out, int out_size, void* d_ws, size_t ws_size,
                              hipStream_t stream) {
    const float* x       = (const float*)d_in[0];
    const float* sm      = (const float*)d_in[1];
    const float* padding = (const float*)d_in[2];
    const float* ratio   = (const float*)d_in[3];
    const int*   piw     = (const int*)d_in[4];
    const int*   pih     = (const int*)d_in[5];
    float* out = (float*)d_out;
    char* ws = (char*)d_ws;

    // workspace layout (bytes)
    float* score               = (float*)(ws + 0);                 // 409600
    int*   clsidx              = (int*)(ws + 409600);              // 409600
    unsigned* hist             = (unsigned*)(ws + 819200);         // 262144
    unsigned* meta             = (unsigned*)(ws + 1081344);        // 512 (meta[0]=counter, meta[1]=p16)
    unsigned long long* cand   = (unsigned long long*)(ws + 1081856); // CAP*8 = 131072
    float* topv                = (float*)(ws + 1212928);           // 16384
    float* bl                  = (float*)(ws + 1229312);
    float* bt                  = (float*)(ws + 1245696);
    float* br                  = (float*)(ws + 1262080);
    float* bb                  = (float*)(ws + 1278464);
    float* area                = (float*)(ws + 1294848);
    int*   clsk                = (int*)(ws + 1311232);
    unsigned long long* keptW  = (unsigned long long*)(ws + 1327616); // 512
    unsigned long long* mask   = (unsigned long long*)(ws + 1328128); // 2097152

    hipMemsetAsync(hist, 0, 262144 + 512, stream);  // hist + meta

    k_score  <<<400, 256, 0, stream>>>(x, sm, score, clsidx, hist);
    k_findp  <<<1, 1024, 0, stream>>>(hist, meta);
    k_collect<<<400, 256, 0, stream>>>(score, meta, cand);
    k_rank   <<<CAP / 256, 256, 0, stream>>>(cand, meta, x, score, clsidx,
                                             topv, bl, bt, br, bb, area, clsk);
    k_mask   <<<256, 256, 0, stream>>>(bl, bt, br, bb, area, mask);
    k_nms    <<<1, 64, 0, stream>>>(mask, topv, area, keptW);
    k_out    <<<16, 256, 0, stream>>>(keptW, topv, bl, bt, br, bb, clsk,
                                      padding, ratio, piw, pih, out);
}

// Round 6
// 712.688 us; speedup vs baseline: 1.6972x; 1.6972x over previous
//
#include <hip/hip_runtime.h>
#include <hip/hip_bf16.h>
#include <math.h>

#define HW 102400        // 320*320
#define KSEL 4096
#define CAP 16384

// ---------- helpers ----------
__device__ inline unsigned fkey(float f) {
    unsigned u = __float_as_uint(f);
    return (u & 0x80000000u) ? ~u : (u | 0x80000000u);
}

// wave64 sum via DPP (row_shr 1/2/4/8 + row_bcast 15/31); result valid in lane 63,
// returned through readlane -> SGPR (wave-uniform, enables scalar branch).
__device__ inline unsigned wave_sum64_s(unsigned x) {
    x += (unsigned)__builtin_amdgcn_update_dpp(0, (int)x, 0x111, 0xf, 0xf, false);
    x += (unsigned)__builtin_amdgcn_update_dpp(0, (int)x, 0x112, 0xf, 0xf, false);
    x += (unsigned)__builtin_amdgcn_update_dpp(0, (int)x, 0x114, 0xf, 0xf, false);
    x += (unsigned)__builtin_amdgcn_update_dpp(0, (int)x, 0x118, 0xf, 0xf, false);
    x += (unsigned)__builtin_amdgcn_update_dpp(0, (int)x, 0x142, 0xa, 0xf, false);
    x += (unsigned)__builtin_amdgcn_update_dpp(0, (int)x, 0x143, 0xc, 0xf, false);
    return (unsigned)__builtin_amdgcn_readlane((int)x, 63);
}

// ---------- K1: score + class argmax (NO histogram — moved to k_hist) ----------
// Block = 256 pixels. Channels staged through LDS in 16-channel double-buffered
// tiles. Per-pixel accumulation is the exact sequential c=0..255 fmaf chain
// (bit-stable, absmax 0.0 across rounds). Argmax ascending, strictly greater.
__global__ __launch_bounds__(256) void k_score(const float* __restrict__ x,
                                               const float* __restrict__ sm,
                                               float* __restrict__ score,
                                               int* __restrict__ clsidx) {
    __shared__ float swt[256][16];      // swt[c][k] = sm[k*256+c]
    __shared__ float tile[2][16][256];  // [buf][channel-in-tile][pixel]
    int t = threadIdx.x;
    for (int i = t; i < 4096; i += 256) {
        int k = i >> 8, c = i & 255;
        swt[c][k] = sm[i];              // sm[i] == sm[k*256+c]
    }
    int wave = t >> 6, lane = t & 63;
    size_t pxb = (size_t)blockIdx.x * 256;
    const float* xc = x + (size_t)5 * HW + pxb;   // class-channel base for this block

    float4 st[4];
#pragma unroll
    for (int j = 0; j < 4; ++j)
        st[j] = *(const float4*)(xc + (size_t)(wave * 4 + j) * HW + lane * 4);
#pragma unroll
    for (int j = 0; j < 4; ++j)
        ((float4*)&tile[0][wave * 4 + j][0])[lane] = st[j];
    __syncthreads();

    float acc[16];
#pragma unroll
    for (int k = 0; k < 16; ++k) acc[k] = 0.f;

    for (int ct = 0; ct < 16; ++ct) {
        int buf = ct & 1;
        if (ct + 1 < 16) {
#pragma unroll
            for (int j = 0; j < 4; ++j)
                st[j] = *(const float4*)(xc + (size_t)((ct + 1) * 16 + wave * 4 + j) * HW + lane * 4);
        }
#pragma unroll
        for (int cc = 0; cc < 16; ++cc) {
            float xv = tile[buf][cc][t];
            const float4* w4 = (const float4*)&swt[ct * 16 + cc][0];
            float4 w0 = w4[0], w1 = w4[1], w2 = w4[2], w3 = w4[3];
            acc[0]  = fmaf(xv, w0.x, acc[0]);  acc[1]  = fmaf(xv, w0.y, acc[1]);
            acc[2]  = fmaf(xv, w0.z, acc[2]);  acc[3]  = fmaf(xv, w0.w, acc[3]);
            acc[4]  = fmaf(xv, w1.x, acc[4]);  acc[5]  = fmaf(xv, w1.y, acc[5]);
            acc[6]  = fmaf(xv, w1.z, acc[6]);  acc[7]  = fmaf(xv, w1.w, acc[7]);
            acc[8]  = fmaf(xv, w2.x, acc[8]);  acc[9]  = fmaf(xv, w2.y, acc[9]);
            acc[10] = fmaf(xv, w2.z, acc[10]); acc[11] = fmaf(xv, w2.w, acc[11]);
            acc[12] = fmaf(xv, w3.x, acc[12]); acc[13] = fmaf(xv, w3.y, acc[13]);
            acc[14] = fmaf(xv, w3.z, acc[14]); acc[15] = fmaf(xv, w3.w, acc[15]);
        }
        __syncthreads();
        if (ct + 1 < 16) {
#pragma unroll
            for (int j = 0; j < 4; ++j)
                ((float4*)&tile[buf ^ 1][wave * 4 + j][0])[lane] = st[j];
            __syncthreads();
        }
    }

    float mv = acc[0]; int mi = 0;
#pragma unroll
    for (int k = 1; k < 16; ++k)
        if (acc[k] > mv) { mv = acc[k]; mi = k; }
    int n = (int)pxb + t;
    float x0 = x[n];
    float sig = 1.0f / (1.0f + expf(-x0));
    float sc = (sig > 0.5f) ? sig * mv : -INFINITY;
    score[n] = sc;
    clsidx[n] = mi;
}

// ---------- K2: histogram, VALID (finite) scores only ----------
// ~51K dead pixels previously hammered the -inf bin with same-address device
// atomics (serialized at coherence point) — that bin is never reachable by
// k_findp's descending scan (51K finite candidates >> 4096), so skip it.
__global__ void k_hist(const float* __restrict__ score, unsigned* __restrict__ hist) {
    int n = blockIdx.x * 256 + threadIdx.x;
    float sc = score[n];
    if (sc != -INFINITY) atomicAdd(&hist[fkey(sc) >> 16], 1u);
}

// ---------- K3: find 16-bit prefix p16 such that count(key>>16 >= p16) >= K ----------
__global__ __launch_bounds__(1024) void k_findp(const unsigned* __restrict__ hist,
                                                unsigned* __restrict__ meta) {
    __shared__ unsigned part[1024];
    __shared__ unsigned sgrp, s_after;
    __shared__ unsigned bins[64];
    int t = threadIdx.x;
    if (t == 0) { sgrp = 0; s_after = 0; }
    unsigned s = 0;
    const unsigned* hp = hist + t * 64;
    for (int i = 0; i < 64; ++i) s += hp[i];
    part[t] = s;
    __syncthreads();
    for (int off = 1; off < 1024; off <<= 1) {
        unsigned v = (t + off < 1024) ? part[t + off] : 0u;
        __syncthreads();
        part[t] += v;
        __syncthreads();
    }
    if (part[t] >= KSEL && (t == 1023 || part[t + 1] < KSEL)) {
        sgrp = (unsigned)t;
        s_after = (t == 1023) ? 0u : part[t + 1];
    }
    __syncthreads();
    unsigned g = sgrp, SA = s_after;
    if (t < 64) bins[t] = hist[g * 64 + t];
    __syncthreads();
    if (t == 0) {
        unsigned acc = SA, p = g * 64;
        for (int b = 63; b >= 0; --b) {
            acc += bins[b];
            if (acc >= KSEL) { p = g * 64 + (unsigned)b; break; }
        }
        meta[1] = p;
    }
}

// ---------- K4: collect candidates with key>>16 >= p16 ----------
__global__ void k_collect(const float* __restrict__ score,
                          unsigned* __restrict__ meta,
                          unsigned long long* __restrict__ cand) {
    int n = blockIdx.x * 256 + threadIdx.x;
    unsigned key = fkey(score[n]);
    if ((key >> 16) >= meta[1]) {
        unsigned pos = atomicAdd(&meta[0], 1u);
        if (pos < CAP)
            cand[pos] = ((unsigned long long)key << 32) | (unsigned)(~(unsigned)n);
    }
}

// ---------- K5: rank candidates (exact top-k ordering) + gather ----------
__global__ __launch_bounds__(256) void k_rank(const unsigned long long* __restrict__ cand,
                                              const unsigned* __restrict__ meta,
                                              const float* __restrict__ x,
                                              const float* __restrict__ score,
                                              const int* __restrict__ clsidx,
                                              float* __restrict__ topv,
                                              float* __restrict__ bl, float* __restrict__ bt,
                                              float* __restrict__ br, float* __restrict__ bb,
                                              float* __restrict__ area, int* __restrict__ clsk) {
    __shared__ unsigned long long tile[1024];
    int C = (int)meta[0]; if (C > CAP) C = CAP;
    int j = blockIdx.x * 256 + threadIdx.x;
    unsigned long long kj = (j < C) ? cand[j] : 0ull;
    unsigned rank = 0;
    for (int tb = 0; tb < C; tb += 1024) {
        int cnt = min(1024, C - tb);
        __syncthreads();
        for (int u = threadIdx.x; u < cnt; u += 256) tile[u] = cand[tb + u];
        __syncthreads();
        if (j < C)
            for (int u = 0; u < cnt; ++u) rank += (tile[u] > kj) ? 1u : 0u;
    }
    if (j < C && rank < KSEL) {
        unsigned n = ~(unsigned)(kj & 0xFFFFFFFFull);
        float l  = x[(size_t)1 * HW + n];
        float tt = x[(size_t)2 * HW + n];
        float r  = x[(size_t)3 * HW + n];
        float b  = x[(size_t)4 * HW + n];
        topv[rank] = score[n];
        bl[rank] = l; bt[rank] = tt; br[rank] = r; bb[rank] = b;
        area[rank] = (r - l) * (b - tt);
        clsk[rank] = clsidx[n];
    }
}

// ---------- K6: pairwise IoU >= 0.2 bitmask, ROW-MAJOR mask[i][w] ----------
__global__ __launch_bounds__(256) void k_mask(const float* __restrict__ bl, const float* __restrict__ bt,
                                              const float* __restrict__ br, const float* __restrict__ bb,
                                              const float* __restrict__ area,
                                              unsigned long long* __restrict__ mask) {
    __shared__ float sl[256], st[256], sr[256], sb[256], sa[256];
    int t = threadIdx.x;
    int ic = blockIdx.x >> 4;
    int jc = blockIdx.x & 15;
    int i = ic * 256 + t;
    int j0 = jc * 256;
    sl[t] = bl[j0 + t]; st[t] = bt[j0 + t]; sr[t] = br[j0 + t];
    sb[t] = bb[j0 + t]; sa[t] = area[j0 + t];
    __syncthreads();
    float li = bl[i], ti = bt[i], ri = br[i], bi = bb[i], ai = area[i];
#pragma unroll
    for (int w = 0; w < 4; ++w) {
        unsigned long long m = 0;
        for (int k2 = 0; k2 < 64; ++k2) {
            int j = w * 64 + k2;
            float iw = fminf(ri, sr[j]) - fmaxf(li, sl[j]); iw = fmaxf(iw, 0.f);
            float ih = fminf(bi, sb[j]) - fmaxf(ti, st[j]); ih = fmaxf(ih, 0.f);
            float inter = iw * ih;
            float uni = ai + sa[j] - inter + 1e-10f;
            if (inter / uni >= 0.2f) m |= (1ull << k2);
        }
        mask[(size_t)i * 64 + (jc * 4 + w)] = m;
    }
}

// ---------- K7: sequential greedy scan, 1 wave, 32-row named-register prefetch ----------
__global__ __launch_bounds__(64, 1) void k_nms(const unsigned long long* __restrict__ mask,
                                               const float* __restrict__ topv,
                                               const float* __restrict__ area,
                                               unsigned long long* __restrict__ keptW) {
    int lane = threadIdx.x;
    unsigned long long alive = 0, areaok = 0, kept = 0;
    for (int k = 0; k < 64; ++k) {
        float tv = topv[(size_t)k * 64 + lane];
        float ar = area[(size_t)k * 64 + lane];
        unsigned long long b1 = __ballot(tv != -INFINITY);
        unsigned long long b2 = __ballot(ar >= 4.0f);
        if (lane == k) { alive = b1; areaok = b2; }
    }
    const unsigned long long* mrow = mask + lane;   // mask[i*64 + lane]
    unsigned long long cw = 0, caw = 0;
    unsigned long long a0,a1,a2,a3,a4,a5,a6,a7;
    unsigned long long b0,b1,b2,b3,b4,b5,b6,b7;
    unsigned long long c0,c1,c2,c3,c4,c5,c6,c7;
    unsigned long long d0,d1,d2,d3,d4,d5,d6,d7;

#define LD8(p, rb)                                                        \
    p##0 = mrow[(size_t)((rb)+0) * 64]; p##1 = mrow[(size_t)((rb)+1) * 64]; \
    p##2 = mrow[(size_t)((rb)+2) * 64]; p##3 = mrow[(size_t)((rb)+3) * 64]; \
    p##4 = mrow[(size_t)((rb)+4) * 64]; p##5 = mrow[(size_t)((rb)+5) * 64]; \
    p##6 = mrow[(size_t)((rb)+6) * 64]; p##7 = mrow[(size_t)((rb)+7) * 64];

#define PR(v, i)                                                          \
    {                                                                     \
        int w = (i) >> 6, b = (i) & 63;                                   \
        if (b == 0) { cw = __shfl(alive, w); caw = __shfl(areaok, w); }   \
        unsigned long long bit = 1ull << b;                               \
        if (cw & bit) {                                                   \
            if (lane == w) alive &= ~bit;                                 \
            cw &= ~bit;                                                   \
            unsigned c = __popcll(v & alive);                             \
            unsigned tot = wave_sum64_s(c);                               \
            if (tot >= 10u && (caw & bit)) {                              \
                alive &= ~v;                                              \
                unsigned long long mw = __shfl(v, w);                     \
                cw &= ~mw;                                                \
                if (lane == w) kept |= bit;                               \
            }                                                             \
        }                                                                 \
    }

#define PR8(p, rb)                                                        \
    PR(p##0, (rb)+0); PR(p##1, (rb)+1); PR(p##2, (rb)+2); PR(p##3, (rb)+3); \
    PR(p##4, (rb)+4); PR(p##5, (rb)+5); PR(p##6, (rb)+6); PR(p##7, (rb)+7);

    LD8(a, 0); LD8(b, 8); LD8(c, 16); LD8(d, 24);
    for (int base = 0; base < 4096; base += 32) {
        PR8(a, base);
        if (base + 32 < 4096) { LD8(a, base + 32); }
        PR8(b, base + 8);
        if (base + 40 < 4096) { LD8(b, base + 40); }
        PR8(c, base + 16);
        if (base + 48 < 4096) { LD8(c, base + 48); }
        PR8(d, base + 24);
        if (base + 56 < 4096) { LD8(d, base + 56); }
    }
    keptW[lane] = kept;
#undef LD8
#undef PR
#undef PR8
}

// ---------- K8: epilogue ----------
__global__ __launch_bounds__(256) void k_out(const unsigned long long* __restrict__ keptW,
                                             const float* __restrict__ topv,
                                             const float* __restrict__ bl, const float* __restrict__ bt,
                                             const float* __restrict__ br, const float* __restrict__ bb,
                                             const int* __restrict__ clsk,
                                             const float* __restrict__ padding,
                                             const float* __restrict__ ratio,
                                             const int* __restrict__ piw, const int* __restrict__ pih,
                                             float* __restrict__ out) {
    int i = blockIdx.x * 256 + threadIdx.x;
    if (i >= KSEL) return;
    bool kept = (keptW[i >> 6] >> (i & 63)) & 1ull;
    float tv = topv[i];
    bool keep = kept && (tv >= 0.5f);
    float p0 = padding[0], p1 = padding[1];
    float invr = 1.0f / ratio[0];
    float W_ = (float)piw[0], H_ = (float)pih[0];
    float x1 = fmaxf((bl[i] - p0) * invr, 0.f);
    float y1 = fmaxf((bt[i] - p1) * invr, 0.f);
    float x2 = fminf((br[i] - p0) * invr, W_);
    float y2 = fminf((bb[i] - p1) * invr, H_);
    keep = keep && (x1 < W_) && (y1 < H_);
    float* o = out + (size_t)i * 7;
    if (keep) {
        o[0] = 1.0f; o[1] = tv; o[2] = x1; o[3] = y1; o[4] = x2; o[5] = y2;
        o[6] = (float)clsk[i];
    } else {
        o[0] = 0.f; o[1] = 0.f; o[2] = 0.f; o[3] = 0.f; o[4] = 0.f; o[5] = 0.f; o[6] = 0.f;
    }
}

extern "C" void kernel_launch(void* const* d_in, const int* in_sizes, int n_in,
                              void* d_out, int out_size, void* d_ws, size_t ws_size,
                              hipStream_t stream) {
    const float* x       = (const float*)d_in[0];
    const float* sm      = (const float*)d_in[1];
    const float* padding = (const float*)d_in[2];
    const float* ratio   = (const float*)d_in[3];
    const int*   piw     = (const int*)d_in[4];
    const int*   pih     = (const int*)d_in[5];
    float* out = (float*)d_out;
    char* ws = (char*)d_ws;

    // workspace layout (bytes)
    float* score               = (float*)(ws + 0);                 // 409600
    int*   clsidx              = (int*)(ws + 409600);              // 409600
    unsigned* hist             = (unsigned*)(ws + 819200);         // 262144
    unsigned* meta             = (unsigned*)(ws + 1081344);        // 512 (meta[0]=counter, meta[1]=p16)
    unsigned long long* cand   = (unsigned long long*)(ws + 1081856); // CAP*8 = 131072
    float* topv                = (float*)(ws + 1212928);           // 16384
    float* bl                  = (float*)(ws + 1229312);
    float* bt                  = (float*)(ws + 1245696);
    float* br                  = (float*)(ws + 1262080);
    float* bb                  = (float*)(ws + 1278464);
    float* area                = (float*)(ws + 1294848);
    int*   clsk                = (int*)(ws + 1311232);
    unsigned long long* keptW  = (unsigned long long*)(ws + 1327616); // 512
    unsigned long long* mask   = (unsigned long long*)(ws + 1328128); // 2097152

    hipMemsetAsync(hist, 0, 262144 + 512, stream);  // hist + meta

    k_score  <<<400, 256, 0, stream>>>(x, sm, score, clsidx);
    k_hist   <<<400, 256, 0, stream>>>(score, hist);
    k_findp  <<<1, 1024, 0, stream>>>(hist, meta);
    k_collect<<<400, 256, 0, stream>>>(score, meta, cand);
    k_rank   <<<CAP / 256, 256, 0, stream>>>(cand, meta, x, score, clsidx,
                                             topv, bl, bt, br, bb, area, clsk);
    k_mask   <<<256, 256, 0, stream>>>(bl, bt, br, bb, area, mask);
    k_nms    <<<1, 64, 0, stream>>>(mask, topv, area, keptW);
    k_out    <<<16, 256, 0, stream>>>(keptW, topv, bl, bt, br, bb, clsk,
                                      padding, ratio, piw, pih, out);
}

// Round 7
// 620.540 us; speedup vs baseline: 1.9492x; 1.1485x over previous
//
#include <hip/hip_runtime.h>
#include <hip/hip_bf16.h>
#include <math.h>

#define HW 102400        // 320*320
#define KSEL 4096
#define CAP 16384

// ---------- helpers ----------
__device__ inline unsigned fkey(float f) {
    unsigned u = __float_as_uint(f);
    return (u & 0x80000000u) ? ~u : (u | 0x80000000u);
}

// wave64 sum via DPP (row_shr 1/2/4/8 + row_bcast 15/31); result valid in lane 63,
// returned through readlane -> SGPR (wave-uniform, enables scalar branch).
__device__ inline unsigned wave_sum64_s(unsigned x) {
    x += (unsigned)__builtin_amdgcn_update_dpp(0, (int)x, 0x111, 0xf, 0xf, false);
    x += (unsigned)__builtin_amdgcn_update_dpp(0, (int)x, 0x112, 0xf, 0xf, false);
    x += (unsigned)__builtin_amdgcn_update_dpp(0, (int)x, 0x114, 0xf, 0xf, false);
    x += (unsigned)__builtin_amdgcn_update_dpp(0, (int)x, 0x118, 0xf, 0xf, false);
    x += (unsigned)__builtin_amdgcn_update_dpp(0, (int)x, 0x142, 0xa, 0xf, false);
    x += (unsigned)__builtin_amdgcn_update_dpp(0, (int)x, 0x143, 0xc, 0xf, false);
    return (unsigned)__builtin_amdgcn_readlane((int)x, 63);
}

// ---------- K1: score + class argmax ----------
// Block = 256 pixels. Channels staged through LDS in 16-channel double-buffered
// tiles. Per-pixel accumulation is the exact sequential c=0..255 fmaf chain
// (bit-stable, absmax 0.0 across rounds). Argmax ascending, strictly greater.
__global__ __launch_bounds__(256) void k_score(const float* __restrict__ x,
                                               const float* __restrict__ sm,
                                               float* __restrict__ score,
                                               int* __restrict__ clsidx) {
    __shared__ float swt[256][16];      // swt[c][k] = sm[k*256+c]
    __shared__ float tile[2][16][256];  // [buf][channel-in-tile][pixel]
    int t = threadIdx.x;
    for (int i = t; i < 4096; i += 256) {
        int k = i >> 8, c = i & 255;
        swt[c][k] = sm[i];              // sm[i] == sm[k*256+c]
    }
    int wave = t >> 6, lane = t & 63;
    size_t pxb = (size_t)blockIdx.x * 256;
    const float* xc = x + (size_t)5 * HW + pxb;   // class-channel base for this block

    float4 st[4];
#pragma unroll
    for (int j = 0; j < 4; ++j)
        st[j] = *(const float4*)(xc + (size_t)(wave * 4 + j) * HW + lane * 4);
#pragma unroll
    for (int j = 0; j < 4; ++j)
        ((float4*)&tile[0][wave * 4 + j][0])[lane] = st[j];
    __syncthreads();

    float acc[16];
#pragma unroll
    for (int k = 0; k < 16; ++k) acc[k] = 0.f;

    for (int ct = 0; ct < 16; ++ct) {
        int buf = ct & 1;
        if (ct + 1 < 16) {
#pragma unroll
            for (int j = 0; j < 4; ++j)
                st[j] = *(const float4*)(xc + (size_t)((ct + 1) * 16 + wave * 4 + j) * HW + lane * 4);
        }
#pragma unroll
        for (int cc = 0; cc < 16; ++cc) {
            float xv = tile[buf][cc][t];
            const float4* w4 = (const float4*)&swt[ct * 16 + cc][0];
            float4 w0 = w4[0], w1 = w4[1], w2 = w4[2], w3 = w4[3];
            acc[0]  = fmaf(xv, w0.x, acc[0]);  acc[1]  = fmaf(xv, w0.y, acc[1]);
            acc[2]  = fmaf(xv, w0.z, acc[2]);  acc[3]  = fmaf(xv, w0.w, acc[3]);
            acc[4]  = fmaf(xv, w1.x, acc[4]);  acc[5]  = fmaf(xv, w1.y, acc[5]);
            acc[6]  = fmaf(xv, w1.z, acc[6]);  acc[7]  = fmaf(xv, w1.w, acc[7]);
            acc[8]  = fmaf(xv, w2.x, acc[8]);  acc[9]  = fmaf(xv, w2.y, acc[9]);
            acc[10] = fmaf(xv, w2.z, acc[10]); acc[11] = fmaf(xv, w2.w, acc[11]);
            acc[12] = fmaf(xv, w3.x, acc[12]); acc[13] = fmaf(xv, w3.y, acc[13]);
            acc[14] = fmaf(xv, w3.z, acc[14]); acc[15] = fmaf(xv, w3.w, acc[15]);
        }
        __syncthreads();
        if (ct + 1 < 16) {
#pragma unroll
            for (int j = 0; j < 4; ++j)
                ((float4*)&tile[buf ^ 1][wave * 4 + j][0])[lane] = st[j];
            __syncthreads();
        }
    }

    float mv = acc[0]; int mi = 0;
#pragma unroll
    for (int k = 1; k < 16; ++k)
        if (acc[k] > mv) { mv = acc[k]; mi = k; }
    int n = (int)pxb + t;
    float x0 = x[n];
    float sig = 1.0f / (1.0f + expf(-x0));
    float sc = (sig > 0.5f) ? sig * mv : -INFINITY;
    score[n] = sc;
    clsidx[n] = mi;
}

// ---------- K2: histogram, VALID (finite) scores only ----------
__global__ void k_hist(const float* __restrict__ score, unsigned* __restrict__ hist) {
    int n = blockIdx.x * 256 + threadIdx.x;
    float sc = score[n];
    if (sc != -INFINITY) atomicAdd(&hist[fkey(sc) >> 16], 1u);
}

// ---------- K3: find 16-bit prefix p16 such that count(key>>16 >= p16) >= K ----------
__global__ __launch_bounds__(1024) void k_findp(const unsigned* __restrict__ hist,
                                                unsigned* __restrict__ meta) {
    __shared__ unsigned part[1024];
    __shared__ unsigned sgrp, s_after;
    __shared__ unsigned bins[64];
    int t = threadIdx.x;
    if (t == 0) { sgrp = 0; s_after = 0; }
    unsigned s = 0;
    const unsigned* hp = hist + t * 64;
    for (int i = 0; i < 64; ++i) s += hp[i];
    part[t] = s;
    __syncthreads();
    for (int off = 1; off < 1024; off <<= 1) {
        unsigned v = (t + off < 1024) ? part[t + off] : 0u;
        __syncthreads();
        part[t] += v;
        __syncthreads();
    }
    if (part[t] >= KSEL && (t == 1023 || part[t + 1] < KSEL)) {
        sgrp = (unsigned)t;
        s_after = (t == 1023) ? 0u : part[t + 1];
    }
    __syncthreads();
    unsigned g = sgrp, SA = s_after;
    if (t < 64) bins[t] = hist[g * 64 + t];
    __syncthreads();
    if (t == 0) {
        unsigned acc = SA, p = g * 64;
        for (int b = 63; b >= 0; --b) {
            acc += bins[b];
            if (acc >= KSEL) { p = g * 64 + (unsigned)b; break; }
        }
        meta[1] = p;
    }
}

// ---------- K4: collect candidates with key>>16 >= p16 ----------
__global__ void k_collect(const float* __restrict__ score,
                          unsigned* __restrict__ meta,
                          unsigned long long* __restrict__ cand) {
    int n = blockIdx.x * 256 + threadIdx.x;
    unsigned key = fkey(score[n]);
    if ((key >> 16) >= meta[1]) {
        unsigned pos = atomicAdd(&meta[0], 1u);
        if (pos < CAP)
            cand[pos] = ((unsigned long long)key << 32) | (unsigned)(~(unsigned)n);
    }
}

// ---------- K5: rank candidates (exact top-k ordering) + gather ----------
__global__ __launch_bounds__(256) void k_rank(const unsigned long long* __restrict__ cand,
                                              const unsigned* __restrict__ meta,
                                              const float* __restrict__ x,
                                              const float* __restrict__ score,
                                              const int* __restrict__ clsidx,
                                              float* __restrict__ topv,
                                              float* __restrict__ bl, float* __restrict__ bt,
                                              float* __restrict__ br, float* __restrict__ bb,
                                              float* __restrict__ area, int* __restrict__ clsk) {
    __shared__ unsigned long long tile[1024];
    int C = (int)meta[0]; if (C > CAP) C = CAP;
    int j = blockIdx.x * 256 + threadIdx.x;
    unsigned long long kj = (j < C) ? cand[j] : 0ull;
    unsigned rank = 0;
    for (int tb = 0; tb < C; tb += 1024) {
        int cnt = min(1024, C - tb);
        __syncthreads();
        for (int u = threadIdx.x; u < cnt; u += 256) tile[u] = cand[tb + u];
        __syncthreads();
        if (j < C)
            for (int u = 0; u < cnt; ++u) rank += (tile[u] > kj) ? 1u : 0u;
    }
    if (j < C && rank < KSEL) {
        unsigned n = ~(unsigned)(kj & 0xFFFFFFFFull);
        float l  = x[(size_t)1 * HW + n];
        float tt = x[(size_t)2 * HW + n];
        float r  = x[(size_t)3 * HW + n];
        float b  = x[(size_t)4 * HW + n];
        topv[rank] = score[n];
        bl[rank] = l; bt[rank] = tt; br[rank] = r; bb[rank] = b;
        area[rank] = (r - l) * (b - tt);
        clsk[rank] = clsidx[n];
    }
}

// ---------- K6: pairwise IoU >= 0.2 bitmask, ROW-MAJOR mask[i][w] ----------
__global__ __launch_bounds__(256) void k_mask(const float* __restrict__ bl, const float* __restrict__ bt,
                                              const float* __restrict__ br, const float* __restrict__ bb,
                                              const float* __restrict__ area,
                                              unsigned long long* __restrict__ mask) {
    __shared__ float sl[256], st[256], sr[256], sb[256], sa[256];
    int t = threadIdx.x;
    int ic = blockIdx.x >> 4;
    int jc = blockIdx.x & 15;
    int i = ic * 256 + t;
    int j0 = jc * 256;
    sl[t] = bl[j0 + t]; st[t] = bt[j0 + t]; sr[t] = br[j0 + t];
    sb[t] = bb[j0 + t]; sa[t] = area[j0 + t];
    __syncthreads();
    float li = bl[i], ti = bt[i], ri = br[i], bi = bb[i], ai = area[i];
#pragma unroll
    for (int w = 0; w < 4; ++w) {
        unsigned long long m = 0;
        for (int k2 = 0; k2 < 64; ++k2) {
            int j = w * 64 + k2;
            float iw = fminf(ri, sr[j]) - fmaxf(li, sl[j]); iw = fmaxf(iw, 0.f);
            float ih = fminf(bi, sb[j]) - fmaxf(ti, st[j]); ih = fmaxf(ih, 0.f);
            float inter = iw * ih;
            float uni = ai + sa[j] - inter + 1e-10f;
            if (inter / uni >= 0.2f) m |= (1ull << k2);
        }
        mask[(size_t)i * 64 + (jc * 4 + w)] = m;
    }
}

// ---------- K7: sequential greedy scan, 1 wave ----------
// 32-row prefetch FORCED via inline-asm global_load_dwordx2 (volatile asm pins
// issue order) + counted s_waitcnt vmcnt(N) whose asm carries the batch regs as
// "+v" data deps (consumer can't be hoisted above the wait; rule #18 fence after).
__global__ __launch_bounds__(64, 1) void k_nms(const unsigned long long* __restrict__ mask,
                                               const float* __restrict__ topv,
                                               const float* __restrict__ area,
                                               unsigned long long* __restrict__ keptW) {
    int lane = threadIdx.x;
    unsigned long long alive = 0, areaok = 0, kept = 0;
    for (int k = 0; k < 64; ++k) {
        float tv = topv[(size_t)k * 64 + lane];
        float ar = area[(size_t)k * 64 + lane];
        unsigned long long b1 = __ballot(tv != -INFINITY);
        unsigned long long b2 = __ballot(ar >= 4.0f);
        if (lane == k) { alive = b1; areaok = b2; }
    }
    const unsigned long long* mrow = mask + lane;   // mask[i*64 + lane]
    unsigned long long cw = 0, caw = 0;
    unsigned long long a0,a1,a2,a3,a4,a5,a6,a7;
    unsigned long long b0,b1,b2,b3,b4,b5,b6,b7;
    unsigned long long c0,c1,c2,c3,c4,c5,c6,c7;
    unsigned long long d0,d1,d2,d3,d4,d5,d6,d7;

// issue 8 row loads (rows rb..rb+7): one address, 13-bit imm offsets (<=3584B)
#define LD8A(p, rb)                                                        \
    do {                                                                   \
        const unsigned long long* ap = mrow + (size_t)(rb) * 64;           \
        asm volatile(                                                      \
            "global_load_dwordx2 %0, %8, off\n\t"                          \
            "global_load_dwordx2 %1, %8, off offset:512\n\t"               \
            "global_load_dwordx2 %2, %8, off offset:1024\n\t"              \
            "global_load_dwordx2 %3, %8, off offset:1536\n\t"              \
            "global_load_dwordx2 %4, %8, off offset:2048\n\t"              \
            "global_load_dwordx2 %5, %8, off offset:2560\n\t"              \
            "global_load_dwordx2 %6, %8, off offset:3072\n\t"              \
            "global_load_dwordx2 %7, %8, off offset:3584"                  \
            : "=v"(p##0), "=v"(p##1), "=v"(p##2), "=v"(p##3),              \
              "=v"(p##4), "=v"(p##5), "=v"(p##6), "=v"(p##7)               \
            : "v"(ap) : "memory");                                         \
    } while (0)

// counted wait; batch regs tied "+v" so uses are ordered after the wait
#define WAIT8(N, p)                                                        \
    do {                                                                   \
        asm volatile("s_waitcnt vmcnt(" #N ")"                             \
            : "+v"(p##0), "+v"(p##1), "+v"(p##2), "+v"(p##3),              \
              "+v"(p##4), "+v"(p##5), "+v"(p##6), "+v"(p##7));             \
        __builtin_amdgcn_sched_barrier(0);                                 \
    } while (0)

#define PR(v, i)                                                           \
    {                                                                      \
        int w = (i) >> 6, b = (i) & 63;                                    \
        if (b == 0) { cw = __shfl(alive, w); caw = __shfl(areaok, w); }    \
        unsigned long long bit = 1ull << b;                                \
        if (cw & bit) {                                                    \
            if (lane == w) alive &= ~bit;                                  \
            cw &= ~bit;                                                    \
            unsigned c = __popcll(v & alive);                              \
            unsigned tot = wave_sum64_s(c);                                \
            if (tot >= 10u && (caw & bit)) {                               \
                alive &= ~v;                                               \
                unsigned long long mw = __shfl(v, w);                      \
                cw &= ~mw;                                                 \
                if (lane == w) kept |= bit;                                \
            }                                                              \
        }                                                                  \
    }

#define PR8(p, rb)                                                         \
    PR(p##0, (rb)+0); PR(p##1, (rb)+1); PR(p##2, (rb)+2); PR(p##3, (rb)+3); \
    PR(p##4, (rb)+4); PR(p##5, (rb)+5); PR(p##6, (rb)+6); PR(p##7, (rb)+7);

    LD8A(a, 0); LD8A(b, 8); LD8A(c, 16); LD8A(d, 24);
    for (int base = 0; base + 32 < 4096; base += 32) {
        WAIT8(24, a); PR8(a, base);      LD8A(a, base + 32);
        WAIT8(24, b); PR8(b, base + 8);  LD8A(b, base + 40);
        WAIT8(24, c); PR8(c, base + 16); LD8A(c, base + 48);
        WAIT8(24, d); PR8(d, base + 24); LD8A(d, base + 56);
    }
    // epilogue: rows 4064..4095, no further issues -> decreasing counts
    WAIT8(24, a); PR8(a, 4064);
    WAIT8(16, b); PR8(b, 4072);
    WAIT8(8,  c); PR8(c, 4080);
    WAIT8(0,  d); PR8(d, 4088);

    keptW[lane] = kept;
#undef LD8A
#undef WAIT8
#undef PR
#undef PR8
}

// ---------- K8: epilogue ----------
__global__ __launch_bounds__(256) void k_out(const unsigned long long* __restrict__ keptW,
                                             const float* __restrict__ topv,
                                             const float* __restrict__ bl, const float* __restrict__ bt,
                                             const float* __restrict__ br, const float* __restrict__ bb,
                                             const int* __restrict__ clsk,
                                             const float* __restrict__ padding,
                                             const float* __restrict__ ratio,
                                             const int* __restrict__ piw, const int* __restrict__ pih,
                                             float* __restrict__ out) {
    int i = blockIdx.x * 256 + threadIdx.x;
    if (i >= KSEL) return;
    bool kept = (keptW[i >> 6] >> (i & 63)) & 1ull;
    float tv = topv[i];
    bool keep = kept && (tv >= 0.5f);
    float p0 = padding[0], p1 = padding[1];
    float invr = 1.0f / ratio[0];
    float W_ = (float)piw[0], H_ = (float)pih[0];
    float x1 = fmaxf((bl[i] - p0) * invr, 0.f);
    float y1 = fmaxf((bt[i] - p1) * invr, 0.f);
    float x2 = fminf((br[i] - p0) * invr, W_);
    float y2 = fminf((bb[i] - p1) * invr, H_);
    keep = keep && (x1 < W_) && (y1 < H_);
    float* o = out + (size_t)i * 7;
    if (keep) {
        o[0] = 1.0f; o[1] = tv; o[2] = x1; o[3] = y1; o[4] = x2; o[5] = y2;
        o[6] = (float)clsk[i];
    } else {
        o[0] = 0.f; o[1] = 0.f; o[2] = 0.f; o[3] = 0.f; o[4] = 0.f; o[5] = 0.f; o[6] = 0.f;
    }
}

extern "C" void kernel_launch(void* const* d_in, const int* in_sizes, int n_in,
                              void* d_out, int out_size, void* d_ws, size_t ws_size,
                              hipStream_t stream) {
    const float* x       = (const float*)d_in[0];
    const float* sm      = (const float*)d_in[1];
    const float* padding = (const float*)d_in[2];
    const float* ratio   = (const float*)d_in[3];
    const int*   piw     = (const int*)d_in[4];
    const int*   pih     = (const int*)d_in[5];
    float* out = (float*)d_out;
    char* ws = (char*)d_ws;

    // workspace layout (bytes)
    float* score               = (float*)(ws + 0);                 // 409600
    int*   clsidx              = (int*)(ws + 409600);              // 409600
    unsigned* hist             = (unsigned*)(ws + 819200);         // 262144
    unsigned* meta             = (unsigned*)(ws + 1081344);        // 512 (meta[0]=counter, meta[1]=p16)
    unsigned long long* cand   = (unsigned long long*)(ws + 1081856); // CAP*8 = 131072
    float* topv                = (float*)(ws + 1212928);           // 16384
    float* bl                  = (float*)(ws + 1229312);
    float* bt                  = (float*)(ws + 1245696);
    float* br                  = (float*)(ws + 1262080);
    float* bb                  = (float*)(ws + 1278464);
    float* area                = (float*)(ws + 1294848);
    int*   clsk                = (int*)(ws + 1311232);
    unsigned long long* keptW  = (unsigned long long*)(ws + 1327616); // 512
    unsigned long long* mask   = (unsigned long long*)(ws + 1328128); // 2097152

    hipMemsetAsync(hist, 0, 262144 + 512, stream);  // hist + meta

    k_score  <<<400, 256, 0, stream>>>(x, sm, score, clsidx);
    k_hist   <<<400, 256, 0, stream>>>(score, hist);
    k_findp  <<<1, 1024, 0, stream>>>(hist, meta);
    k_collect<<<400, 256, 0, stream>>>(score, meta, cand);
    k_rank   <<<CAP / 256, 256, 0, stream>>>(cand, meta, x, score, clsidx,
                                             topv, bl, bt, br, bb, area, clsk);
    k_mask   <<<256, 256, 0, stream>>>(bl, bt, br, bb, area, mask);
    k_nms    <<<1, 64, 0, stream>>>(mask, topv, area, keptW);
    k_out    <<<16, 256, 0, stream>>>(keptW, topv, bl, bt, br, bb, clsk,
                                      padding, ratio, piw, pih, out);
}

// Round 8
// 375.863 us; speedup vs baseline: 3.2181x; 1.6510x over previous
//
#include <hip/hip_runtime.h>
#include <hip/hip_bf16.h>
#include <math.h>

#define HW 102400        // 320*320
#define KSEL 4096
#define CAP 16384

// ---------- helpers ----------
__device__ inline unsigned fkey(float f) {
    unsigned u = __float_as_uint(f);
    return (u & 0x80000000u) ? ~u : (u | 0x80000000u);
}

// wave64 sum via DPP (row_shr 1/2/4/8 + row_bcast 15/31); result valid in lane 63,
// returned through readlane -> SGPR (wave-uniform, enables scalar branch).
__device__ inline unsigned wave_sum64_s(unsigned x) {
    x += (unsigned)__builtin_amdgcn_update_dpp(0, (int)x, 0x111, 0xf, 0xf, false);
    x += (unsigned)__builtin_amdgcn_update_dpp(0, (int)x, 0x112, 0xf, 0xf, false);
    x += (unsigned)__builtin_amdgcn_update_dpp(0, (int)x, 0x114, 0xf, 0xf, false);
    x += (unsigned)__builtin_amdgcn_update_dpp(0, (int)x, 0x118, 0xf, 0xf, false);
    x += (unsigned)__builtin_amdgcn_update_dpp(0, (int)x, 0x142, 0xa, 0xf, false);
    x += (unsigned)__builtin_amdgcn_update_dpp(0, (int)x, 0x143, 0xc, 0xf, false);
    return (unsigned)__builtin_amdgcn_readlane((int)x, 63);
}

__device__ inline unsigned long long readlane64(unsigned long long v, int l) {
    unsigned lo = (unsigned)__builtin_amdgcn_readlane((int)(unsigned)(v & 0xffffffffull), l);
    unsigned hi = (unsigned)__builtin_amdgcn_readlane((int)(unsigned)(v >> 32), l);
    return ((unsigned long long)hi << 32) | lo;
}

// ---------- K1: score + class argmax ----------
__global__ __launch_bounds__(256) void k_score(const float* __restrict__ x,
                                               const float* __restrict__ sm,
                                               float* __restrict__ score,
                                               int* __restrict__ clsidx) {
    __shared__ float swt[256][16];      // swt[c][k] = sm[k*256+c]
    __shared__ float tile[2][16][256];  // [buf][channel-in-tile][pixel]
    int t = threadIdx.x;
    for (int i = t; i < 4096; i += 256) {
        int k = i >> 8, c = i & 255;
        swt[c][k] = sm[i];
    }
    int wave = t >> 6, lane = t & 63;
    size_t pxb = (size_t)blockIdx.x * 256;
    const float* xc = x + (size_t)5 * HW + pxb;

    float4 st[4];
#pragma unroll
    for (int j = 0; j < 4; ++j)
        st[j] = *(const float4*)(xc + (size_t)(wave * 4 + j) * HW + lane * 4);
#pragma unroll
    for (int j = 0; j < 4; ++j)
        ((float4*)&tile[0][wave * 4 + j][0])[lane] = st[j];
    __syncthreads();

    float acc[16];
#pragma unroll
    for (int k = 0; k < 16; ++k) acc[k] = 0.f;

    for (int ct = 0; ct < 16; ++ct) {
        int buf = ct & 1;
        if (ct + 1 < 16) {
#pragma unroll
            for (int j = 0; j < 4; ++j)
                st[j] = *(const float4*)(xc + (size_t)((ct + 1) * 16 + wave * 4 + j) * HW + lane * 4);
        }
#pragma unroll
        for (int cc = 0; cc < 16; ++cc) {
            float xv = tile[buf][cc][t];
            const float4* w4 = (const float4*)&swt[ct * 16 + cc][0];
            float4 w0 = w4[0], w1 = w4[1], w2 = w4[2], w3 = w4[3];
            acc[0]  = fmaf(xv, w0.x, acc[0]);  acc[1]  = fmaf(xv, w0.y, acc[1]);
            acc[2]  = fmaf(xv, w0.z, acc[2]);  acc[3]  = fmaf(xv, w0.w, acc[3]);
            acc[4]  = fmaf(xv, w1.x, acc[4]);  acc[5]  = fmaf(xv, w1.y, acc[5]);
            acc[6]  = fmaf(xv, w1.z, acc[6]);  acc[7]  = fmaf(xv, w1.w, acc[7]);
            acc[8]  = fmaf(xv, w2.x, acc[8]);  acc[9]  = fmaf(xv, w2.y, acc[9]);
            acc[10] = fmaf(xv, w2.z, acc[10]); acc[11] = fmaf(xv, w2.w, acc[11]);
            acc[12] = fmaf(xv, w3.x, acc[12]); acc[13] = fmaf(xv, w3.y, acc[13]);
            acc[14] = fmaf(xv, w3.z, acc[14]); acc[15] = fmaf(xv, w3.w, acc[15]);
        }
        __syncthreads();
        if (ct + 1 < 16) {
#pragma unroll
            for (int j = 0; j < 4; ++j)
                ((float4*)&tile[buf ^ 1][wave * 4 + j][0])[lane] = st[j];
            __syncthreads();
        }
    }

    float mv = acc[0]; int mi = 0;
#pragma unroll
    for (int k = 1; k < 16; ++k)
        if (acc[k] > mv) { mv = acc[k]; mi = k; }
    int n = (int)pxb + t;
    float x0 = x[n];
    float sig = 1.0f / (1.0f + expf(-x0));
    float sc = (sig > 0.5f) ? sig * mv : -INFINITY;
    score[n] = sc;
    clsidx[n] = mi;
}

// ---------- K2: histogram, VALID (finite) scores only ----------
__global__ void k_hist(const float* __restrict__ score, unsigned* __restrict__ hist) {
    int n = blockIdx.x * 256 + threadIdx.x;
    float sc = score[n];
    if (sc != -INFINITY) atomicAdd(&hist[fkey(sc) >> 16], 1u);
}

// ---------- K3: find 16-bit prefix p16 such that count(key>>16 >= p16) >= K ----------
__global__ __launch_bounds__(1024) void k_findp(const unsigned* __restrict__ hist,
                                                unsigned* __restrict__ meta) {
    __shared__ unsigned part[1024];
    __shared__ unsigned sgrp, s_after;
    __shared__ unsigned bins[64];
    int t = threadIdx.x;
    if (t == 0) { sgrp = 0; s_after = 0; }
    unsigned s = 0;
    const unsigned* hp = hist + t * 64;
    for (int i = 0; i < 64; ++i) s += hp[i];
    part[t] = s;
    __syncthreads();
    for (int off = 1; off < 1024; off <<= 1) {
        unsigned v = (t + off < 1024) ? part[t + off] : 0u;
        __syncthreads();
        part[t] += v;
        __syncthreads();
    }
    if (part[t] >= KSEL && (t == 1023 || part[t + 1] < KSEL)) {
        sgrp = (unsigned)t;
        s_after = (t == 1023) ? 0u : part[t + 1];
    }
    __syncthreads();
    unsigned g = sgrp, SA = s_after;
    if (t < 64) bins[t] = hist[g * 64 + t];
    __syncthreads();
    if (t == 0) {
        unsigned acc = SA, p = g * 64;
        for (int b = 63; b >= 0; --b) {
            acc += bins[b];
            if (acc >= KSEL) { p = g * 64 + (unsigned)b; break; }
        }
        meta[1] = p;
    }
}

// ---------- K4: collect candidates with key>>16 >= p16 ----------
__global__ void k_collect(const float* __restrict__ score,
                          unsigned* __restrict__ meta,
                          unsigned long long* __restrict__ cand) {
    int n = blockIdx.x * 256 + threadIdx.x;
    unsigned key = fkey(score[n]);
    if ((key >> 16) >= meta[1]) {
        unsigned pos = atomicAdd(&meta[0], 1u);
        if (pos < CAP)
            cand[pos] = ((unsigned long long)key << 32) | (unsigned)(~(unsigned)n);
    }
}

// ---------- K5: rank candidates (exact top-k ordering) + gather ----------
__global__ __launch_bounds__(256) void k_rank(const unsigned long long* __restrict__ cand,
                                              const unsigned* __restrict__ meta,
                                              const float* __restrict__ x,
                                              const float* __restrict__ score,
                                              const int* __restrict__ clsidx,
                                              float* __restrict__ topv,
                                              float* __restrict__ bl, float* __restrict__ bt,
                                              float* __restrict__ br, float* __restrict__ bb,
                                              float* __restrict__ area, int* __restrict__ clsk) {
    __shared__ unsigned long long tile[1024];
    int C = (int)meta[0]; if (C > CAP) C = CAP;
    int j = blockIdx.x * 256 + threadIdx.x;
    unsigned long long kj = (j < C) ? cand[j] : 0ull;
    unsigned rank = 0;
    for (int tb = 0; tb < C; tb += 1024) {
        int cnt = min(1024, C - tb);
        __syncthreads();
        for (int u = threadIdx.x; u < cnt; u += 256) tile[u] = cand[tb + u];
        __syncthreads();
        if (j < C)
            for (int u = 0; u < cnt; ++u) rank += (tile[u] > kj) ? 1u : 0u;
    }
    if (j < C && rank < KSEL) {
        unsigned n = ~(unsigned)(kj & 0xFFFFFFFFull);
        float l  = x[(size_t)1 * HW + n];
        float tt = x[(size_t)2 * HW + n];
        float r  = x[(size_t)3 * HW + n];
        float b  = x[(size_t)4 * HW + n];
        topv[rank] = score[n];
        bl[rank] = l; bt[rank] = tt; br[rank] = r; bb[rank] = b;
        area[rank] = (r - l) * (b - tt);
        clsk[rank] = clsidx[n];
    }
}

// ---------- K6: pairwise IoU >= 0.2 bitmask, ROW-MAJOR mask[i][w] ----------
__global__ __launch_bounds__(256) void k_mask(const float* __restrict__ bl, const float* __restrict__ bt,
                                              const float* __restrict__ br, const float* __restrict__ bb,
                                              const float* __restrict__ area,
                                              unsigned long long* __restrict__ mask) {
    __shared__ float sl[256], st[256], sr[256], sb[256], sa[256];
    int t = threadIdx.x;
    int ic = blockIdx.x >> 4;
    int jc = blockIdx.x & 15;
    int i = ic * 256 + t;
    int j0 = jc * 256;
    sl[t] = bl[j0 + t]; st[t] = bt[j0 + t]; sr[t] = br[j0 + t];
    sb[t] = bb[j0 + t]; sa[t] = area[j0 + t];
    __syncthreads();
    float li = bl[i], ti = bt[i], ri = br[i], bi = bb[i], ai = area[i];
#pragma unroll
    for (int w = 0; w < 4; ++w) {
        unsigned long long m = 0;
        for (int k2 = 0; k2 < 64; ++k2) {
            int j = w * 64 + k2;
            float iw = fminf(ri, sr[j]) - fmaxf(li, sl[j]); iw = fmaxf(iw, 0.f);
            float ih = fminf(bi, sb[j]) - fmaxf(ti, st[j]); ih = fmaxf(ih, 0.f);
            float inter = iw * ih;
            float uni = ai + sa[j] - inter + 1e-10f;
            if (inter / uni >= 0.2f) m |= (1ull << k2);
        }
        mask[(size_t)i * 64 + (jc * 4 + w)] = m;
    }
}

// ---------- K7: batched speculative NMS scan, 1 wave, LDS-staged ----------
// Per 64-row batch b (rows b*64..b*64+63 = alive word b):
//  - rows staged in LDS (global_load_lds, pair-swizzled source, double-buffered)
//  - pre-scan: lane j computes popcount(row_j & alive_stale) fully in parallel
//    (upper bound of the exact count: suppression only clears bits), analytic
//    visited-prefix correction on word b -> ballot of candidate rows
//  - candidates verified in ascending order with exact distributed count
//    (DPP sum); accepts update register-distributed alive immediately.
// Exactly reproduces the sequential reference semantics.
__global__ __launch_bounds__(64, 1) void k_nms(const unsigned long long* __restrict__ mask,
                                               const float* __restrict__ topv,
                                               const float* __restrict__ area,
                                               unsigned long long* __restrict__ keptW) {
    __shared__ unsigned long long rowsL[2][4096];   // 2 x 32KB: 64 rows x 64 words
    int lane = threadIdx.x;

    // ---- stage helper: batch bb -> buffer s. Source pre-swizzled so that LDS
    // (written linearly lane*16) holds logical pair P of row r at phys P^(r&31).
#define STAGE(bb, s)                                                            \
    do {                                                                        \
        _Pragma("unroll") for (int q = 0; q < 32; ++q) {                        \
            int r_ = (bb) * 64 + q * 2 + (lane >> 5);                           \
            int P_ = (lane & 31) ^ (r_ & 31);                                   \
            const unsigned long long* gp_ = mask + (size_t)r_ * 64 + P_ * 2;    \
            __builtin_amdgcn_global_load_lds(                                   \
                (const __attribute__((address_space(1))) void*)gp_,             \
                (__attribute__((address_space(3))) void*)&rowsL[s][q * 128],    \
                16, 0, 0);                                                      \
        }                                                                       \
    } while (0)

    STAGE(0, 0);
    STAGE(1, 1);

    // ---- init alive/areaok, register-distributed: lane w owns word w
    unsigned long long alive = 0, areaok = 0;
    for (int k = 0; k < 64; ++k) {
        float tv = topv[(size_t)k * 64 + lane];
        float ar = area[(size_t)k * 64 + lane];
        unsigned long long b1 = __ballot(tv != -INFINITY);
        unsigned long long b2 = __ballot(ar >= 4.0f);
        if (lane == k) { alive = b1; areaok = b2; }
    }

    for (int b = 0; b < 64; ++b) {
        // wait for batch b's staged rows (one batch stays in flight)
        if (b < 63) {
            asm volatile("s_waitcnt vmcnt(32)" ::: "memory");
        } else {
            asm volatile("s_waitcnt vmcnt(0)" ::: "memory");
        }
        __builtin_amdgcn_sched_barrier(0);

        const unsigned long long* rb = rowsL[b & 1];
        unsigned long long aw0snap = readlane64(alive, b);
        unsigned long long areaok0 = readlane64(areaok, b);

        // ---- pre-scan: lane j handles row b*64+j
        int sw = lane & 31;
        unsigned cnt = 0;
#pragma unroll
        for (int P = 0; P < 32; ++P) {
            const ulonglong2 rv = *(const ulonglong2*)&rb[lane * 64 + ((P ^ sw) << 1)];
            unsigned long long a0 = readlane64(alive, 2 * P);
            unsigned long long a1 = readlane64(alive, 2 * P + 1);
            cnt += (unsigned)__popcll(rv.x & a0) + (unsigned)__popcll(rv.y & a1);
        }
        // visited-prefix correction on word b (bits 0..lane inclusive)
        unsigned long long m_w0 = rb[lane * 64 + ((((b >> 1) ^ sw)) << 1) + (b & 1)];
        unsigned long long pfx = (lane == 63) ? ~0ull : ((1ull << (lane + 1)) - 1ull);
        cnt -= (unsigned)__popcll(m_w0 & aw0snap & pfx);

        bool candp = (cnt >= 10u) && ((areaok0 >> lane) & 1ull) && ((aw0snap >> lane) & 1ull);
        unsigned long long cand = __ballot(candp);
        unsigned long long keptB = 0;

        // ---- ordered exact verification of candidates
        while (cand) {
            int j1 = __ffsll(cand) - 1;
            cand &= cand - 1;
            unsigned long long aw0cur = readlane64(alive, b);
            if (!((aw0cur >> j1) & 1ull)) continue;      // suppressed in-batch
            // lane w reads logical word w of row j1
            unsigned long long rw = rb[(size_t)j1 * 64 + (((lane >> 1) ^ (j1 & 31)) << 1) + (lane & 1)];
            unsigned long long awAdj = alive;
            unsigned long long pm = (j1 == 63) ? ~0ull : ((1ull << (j1 + 1)) - 1ull);
            if (lane == b) awAdj &= ~pm;                 // visited bits of word b
            unsigned c = (unsigned)__popcll(rw & awAdj);
            unsigned tt = wave_sum64_s(c);
            if (tt >= 10u) {
                alive &= ~rw;                            // suppress overlaps
                keptB |= 1ull << j1;
            }
        }

        // batch end: whole word b is now visited
        if (lane == b) alive = 0;
        if (lane == 0) keptW[b] = keptB;

        // prefetch batch b+2 into the buffer just freed (all reads of it done)
        if (b + 2 < 64) { STAGE(b + 2, (b & 1)); }
    }
#undef STAGE
}

// ---------- K8: epilogue ----------
__global__ __launch_bounds__(256) void k_out(const unsigned long long* __restrict__ keptW,
                                             const float* __restrict__ topv,
                                             const float* __restrict__ bl, const float* __restrict__ bt,
                                             const float* __restrict__ br, const float* __restrict__ bb,
                                             const int* __restrict__ clsk,
                                             const float* __restrict__ padding,
                                             const float* __restrict__ ratio,
                                             const int* __restrict__ piw, const int* __restrict__ pih,
                                             float* __restrict__ out) {
    int i = blockIdx.x * 256 + threadIdx.x;
    if (i >= KSEL) return;
    bool kept = (keptW[i >> 6] >> (i & 63)) & 1ull;
    float tv = topv[i];
    bool keep = kept && (tv >= 0.5f);
    float p0 = padding[0], p1 = padding[1];
    float invr = 1.0f / ratio[0];
    float W_ = (float)piw[0], H_ = (float)pih[0];
    float x1 = fmaxf((bl[i] - p0) * invr, 0.f);
    float y1 = fmaxf((bt[i] - p1) * invr, 0.f);
    float x2 = fminf((br[i] - p0) * invr, W_);
    float y2 = fminf((bb[i] - p1) * invr, H_);
    keep = keep && (x1 < W_) && (y1 < H_);
    float* o = out + (size_t)i * 7;
    if (keep) {
        o[0] = 1.0f; o[1] = tv; o[2] = x1; o[3] = y1; o[4] = x2; o[5] = y2;
        o[6] = (float)clsk[i];
    } else {
        o[0] = 0.f; o[1] = 0.f; o[2] = 0.f; o[3] = 0.f; o[4] = 0.f; o[5] = 0.f; o[6] = 0.f;
    }
}

extern "C" void kernel_launch(void* const* d_in, const int* in_sizes, int n_in,
                              void* d_out, int out_size, void* d_ws, size_t ws_size,
                              hipStream_t stream) {
    const float* x       = (const float*)d_in[0];
    const float* sm      = (const float*)d_in[1];
    const float* padding = (const float*)d_in[2];
    const float* ratio   = (const float*)d_in[3];
    const int*   piw     = (const int*)d_in[4];
    const int*   pih     = (const int*)d_in[5];
    float* out = (float*)d_out;
    char* ws = (char*)d_ws;

    // workspace layout (bytes)
    float* score               = (float*)(ws + 0);                 // 409600
    int*   clsidx              = (int*)(ws + 409600);              // 409600
    unsigned* hist             = (unsigned*)(ws + 819200);         // 262144
    unsigned* meta             = (unsigned*)(ws + 1081344);        // 512 (meta[0]=counter, meta[1]=p16)
    unsigned long long* cand   = (unsigned long long*)(ws + 1081856); // CAP*8 = 131072
    float* topv                = (float*)(ws + 1212928);           // 16384
    float* bl                  = (float*)(ws + 1229312);
    float* bt                  = (float*)(ws + 1245696);
    float* br                  = (float*)(ws + 1262080);
    float* bb                  = (float*)(ws + 1278464);
    float* area                = (float*)(ws + 1294848);
    int*   clsk                = (int*)(ws + 1311232);
    unsigned long long* keptW  = (unsigned long long*)(ws + 1327616); // 512
    unsigned long long* mask   = (unsigned long long*)(ws + 1328128); // 2097152

    hipMemsetAsync(hist, 0, 262144 + 512, stream);  // hist + meta

    k_score  <<<400, 256, 0, stream>>>(x, sm, score, clsidx);
    k_hist   <<<400, 256, 0, stream>>>(score, hist);
    k_findp  <<<1, 1024, 0, stream>>>(hist, meta);
    k_collect<<<400, 256, 0, stream>>>(score, meta, cand);
    k_rank   <<<CAP / 256, 256, 0, stream>>>(cand, meta, x, score, clsidx,
                                             topv, bl, bt, br, bb, area, clsk);
    k_mask   <<<256, 256, 0, stream>>>(bl, bt, br, bb, area, mask);
    k_nms    <<<1, 64, 0, stream>>>(mask, topv, area, keptW);
    k_out    <<<16, 256, 0, stream>>>(keptW, topv, bl, bt, br, bb, clsk,
                                      padding, ratio, piw, pih, out);
}

// Round 9
// 374.743 us; speedup vs baseline: 3.2277x; 1.0030x over previous
//
#include <hip/hip_runtime.h>
#include <hip/hip_bf16.h>
#include <math.h>

#define HW 102400        // 320*320
#define KSEL 4096
#define CAP 16384

// ---------- helpers ----------
__device__ inline unsigned fkey(float f) {
    unsigned u = __float_as_uint(f);
    return (u & 0x80000000u) ? ~u : (u | 0x80000000u);
}

// wave64 sum via DPP (row_shr 1/2/4/8 + row_bcast 15/31); result valid in lane 63,
// returned through readlane -> SGPR (wave-uniform, enables scalar branch).
__device__ inline unsigned wave_sum64_s(unsigned x) {
    x += (unsigned)__builtin_amdgcn_update_dpp(0, (int)x, 0x111, 0xf, 0xf, false);
    x += (unsigned)__builtin_amdgcn_update_dpp(0, (int)x, 0x112, 0xf, 0xf, false);
    x += (unsigned)__builtin_amdgcn_update_dpp(0, (int)x, 0x114, 0xf, 0xf, false);
    x += (unsigned)__builtin_amdgcn_update_dpp(0, (int)x, 0x118, 0xf, 0xf, false);
    x += (unsigned)__builtin_amdgcn_update_dpp(0, (int)x, 0x142, 0xa, 0xf, false);
    x += (unsigned)__builtin_amdgcn_update_dpp(0, (int)x, 0x143, 0xc, 0xf, false);
    return (unsigned)__builtin_amdgcn_readlane((int)x, 63);
}

__device__ inline unsigned long long readlane64(unsigned long long v, int l) {
    unsigned lo = (unsigned)__builtin_amdgcn_readlane((int)(unsigned)(v & 0xffffffffull), l);
    unsigned hi = (unsigned)__builtin_amdgcn_readlane((int)(unsigned)(v >> 32), l);
    return ((unsigned long long)hi << 32) | lo;
}

// ---------- K1: score + class argmax ----------
// Block = 256 pixels. 16-channel LDS tiles, 2 buffers, ONE barrier per tile,
// 2-deep named-register prefetch (sa/sb) so HBM latency (~900cy) is covered by
// ~2 tile iterations. Per-pixel accumulation is the exact sequential c=0..255
// fmaf chain (bit-stable across rounds, absmax 0.0). Argmax ascending, strictly
// greater => identical first-max-index semantics.
__global__ __launch_bounds__(256) void k_score(const float* __restrict__ x,
                                               const float* __restrict__ sm,
                                               float* __restrict__ score,
                                               int* __restrict__ clsidx) {
    __shared__ float swt[256][16];      // 16KB: swt[c][k] = sm[k*256+c]
    __shared__ float tile[2][16][256];  // 32KB
    int t = threadIdx.x;
    for (int i = t; i < 4096; i += 256) {
        int k = i >> 8, c = i & 255;
        swt[c][k] = sm[i];
    }
    int wave = t >> 6, lane = t & 63;
    size_t pxb = (size_t)blockIdx.x * 256;
    const float* xc = x + (size_t)5 * HW + pxb;

    float acc[16];
#pragma unroll
    for (int k = 0; k < 16; ++k) acc[k] = 0.f;

    float4 sa[4], sb[4];

#define LOADX(dst, ti)                                                         \
    _Pragma("unroll") for (int j = 0; j < 4; ++j)                              \
        dst[j] = *(const float4*)(xc + (size_t)((ti) * 16 + wave * 4 + j) * HW + lane * 4);
#define STOREX(src, s)                                                         \
    _Pragma("unroll") for (int j = 0; j < 4; ++j)                              \
        ((float4*)&tile[s][wave * 4 + j][0])[lane] = src[j];
#define COMP(s, ti)                                                            \
    _Pragma("unroll") for (int cc = 0; cc < 16; ++cc) {                        \
        float xv = tile[s][cc][t];                                             \
        const float4* w4 = (const float4*)&swt[(ti) * 16 + cc][0];             \
        float4 w0 = w4[0], w1 = w4[1], w2 = w4[2], w3 = w4[3];                 \
        acc[0]  = fmaf(xv, w0.x, acc[0]);  acc[1]  = fmaf(xv, w0.y, acc[1]);   \
        acc[2]  = fmaf(xv, w0.z, acc[2]);  acc[3]  = fmaf(xv, w0.w, acc[3]);   \
        acc[4]  = fmaf(xv, w1.x, acc[4]);  acc[5]  = fmaf(xv, w1.y, acc[5]);   \
        acc[6]  = fmaf(xv, w1.z, acc[6]);  acc[7]  = fmaf(xv, w1.w, acc[7]);   \
        acc[8]  = fmaf(xv, w2.x, acc[8]);  acc[9]  = fmaf(xv, w2.y, acc[9]);   \
        acc[10] = fmaf(xv, w2.z, acc[10]); acc[11] = fmaf(xv, w2.w, acc[11]);  \
        acc[12] = fmaf(xv, w3.x, acc[12]); acc[13] = fmaf(xv, w3.y, acc[13]);  \
        acc[14] = fmaf(xv, w3.z, acc[14]); acc[15] = fmaf(xv, w3.w, acc[15]);  \
    }

    // prologue: tile0 -> buf0; sa <- tile1; sb <- tile2
    LOADX(sa, 0);
    STOREX(sa, 0);
    LOADX(sa, 1);
    LOADX(sb, 2);
    __syncthreads();

    // invariant at top of iter k (even): buf[k%2]=tile k, sa=tile k+1, sb=tile k+2
#pragma unroll
    for (int k = 0; k < 16; k += 2) {
        COMP(k & 1, k);
        STOREX(sa, (k + 1) & 1);            // tile k+1
        if (k + 3 < 16) LOADX(sa, k + 3);
        __syncthreads();
        COMP((k + 1) & 1, k + 1);
        if (k + 2 < 16) { STOREX(sb, k & 1); }   // tile k+2
        if (k + 4 < 16) LOADX(sb, k + 4);
        __syncthreads();
    }
#undef LOADX
#undef STOREX
#undef COMP

    float mv = acc[0]; int mi = 0;
#pragma unroll
    for (int k = 1; k < 16; ++k)
        if (acc[k] > mv) { mv = acc[k]; mi = k; }
    int n = (int)pxb + t;
    float x0 = x[n];
    float sig = 1.0f / (1.0f + expf(-x0));
    float sc = (sig > 0.5f) ? sig * mv : -INFINITY;
    score[n] = sc;
    clsidx[n] = mi;
}

// ---------- K2: histogram, VALID (finite) scores only ----------
__global__ void k_hist(const float* __restrict__ score, unsigned* __restrict__ hist) {
    int n = blockIdx.x * 256 + threadIdx.x;
    float sc = score[n];
    if (sc != -INFINITY) atomicAdd(&hist[fkey(sc) >> 16], 1u);
}

// ---------- K3: find 16-bit prefix p16 such that count(key>>16 >= p16) >= K ----------
__global__ __launch_bounds__(1024) void k_findp(const unsigned* __restrict__ hist,
                                                unsigned* __restrict__ meta) {
    __shared__ unsigned part[1024];
    __shared__ unsigned sgrp, s_after;
    __shared__ unsigned bins[64];
    int t = threadIdx.x;
    if (t == 0) { sgrp = 0; s_after = 0; }
    unsigned s = 0;
    const unsigned* hp = hist + t * 64;
    for (int i = 0; i < 64; ++i) s += hp[i];
    part[t] = s;
    __syncthreads();
    for (int off = 1; off < 1024; off <<= 1) {
        unsigned v = (t + off < 1024) ? part[t + off] : 0u;
        __syncthreads();
        part[t] += v;
        __syncthreads();
    }
    if (part[t] >= KSEL && (t == 1023 || part[t + 1] < KSEL)) {
        sgrp = (unsigned)t;
        s_after = (t == 1023) ? 0u : part[t + 1];
    }
    __syncthreads();
    unsigned g = sgrp, SA = s_after;
    if (t < 64) bins[t] = hist[g * 64 + t];
    __syncthreads();
    if (t == 0) {
        unsigned acc = SA, p = g * 64;
        for (int b = 63; b >= 0; --b) {
            acc += bins[b];
            if (acc >= KSEL) { p = g * 64 + (unsigned)b; break; }
        }
        meta[1] = p;
    }
}

// ---------- K4: collect candidates with key>>16 >= p16 ----------
__global__ void k_collect(const float* __restrict__ score,
                          unsigned* __restrict__ meta,
                          unsigned long long* __restrict__ cand) {
    int n = blockIdx.x * 256 + threadIdx.x;
    unsigned key = fkey(score[n]);
    if ((key >> 16) >= meta[1]) {
        unsigned pos = atomicAdd(&meta[0], 1u);
        if (pos < CAP)
            cand[pos] = ((unsigned long long)key << 32) | (unsigned)(~(unsigned)n);
    }
}

// ---------- K5: rank candidates (exact top-k ordering) + gather ----------
__global__ __launch_bounds__(256) void k_rank(const unsigned long long* __restrict__ cand,
                                              const unsigned* __restrict__ meta,
                                              const float* __restrict__ x,
                                              const float* __restrict__ score,
                                              const int* __restrict__ clsidx,
                                              float* __restrict__ topv,
                                              float* __restrict__ bl, float* __restrict__ bt,
                                              float* __restrict__ br, float* __restrict__ bb,
                                              float* __restrict__ area, int* __restrict__ clsk) {
    __shared__ unsigned long long tile[1024];
    int C = (int)meta[0]; if (C > CAP) C = CAP;
    int j = blockIdx.x * 256 + threadIdx.x;
    unsigned long long kj = (j < C) ? cand[j] : 0ull;
    unsigned rank = 0;
    for (int tb = 0; tb < C; tb += 1024) {
        int cnt = min(1024, C - tb);
        __syncthreads();
        for (int u = threadIdx.x; u < cnt; u += 256) tile[u] = cand[tb + u];
        __syncthreads();
        if (j < C)
            for (int u = 0; u < cnt; ++u) rank += (tile[u] > kj) ? 1u : 0u;
    }
    if (j < C && rank < KSEL) {
        unsigned n = ~(unsigned)(kj & 0xFFFFFFFFull);
        float l  = x[(size_t)1 * HW + n];
        float tt = x[(size_t)2 * HW + n];
        float r  = x[(size_t)3 * HW + n];
        float b  = x[(size_t)4 * HW + n];
        topv[rank] = score[n];
        bl[rank] = l; bt[rank] = tt; br[rank] = r; bb[rank] = b;
        area[rank] = (r - l) * (b - tt);
        clsk[rank] = clsidx[n];
    }
}

// ---------- K6: pairwise IoU >= 0.2 bitmask, ROW-MAJOR mask[i][w] ----------
__global__ __launch_bounds__(256) void k_mask(const float* __restrict__ bl, const float* __restrict__ bt,
                                              const float* __restrict__ br, const float* __restrict__ bb,
                                              const float* __restrict__ area,
                                              unsigned long long* __restrict__ mask) {
    __shared__ float sl[256], st[256], sr[256], sb[256], sa[256];
    int t = threadIdx.x;
    int ic = blockIdx.x >> 4;
    int jc = blockIdx.x & 15;
    int i = ic * 256 + t;
    int j0 = jc * 256;
    sl[t] = bl[j0 + t]; st[t] = bt[j0 + t]; sr[t] = br[j0 + t];
    sb[t] = bb[j0 + t]; sa[t] = area[j0 + t];
    __syncthreads();
    float li = bl[i], ti = bt[i], ri = br[i], bi = bb[i], ai = area[i];
#pragma unroll
    for (int w = 0; w < 4; ++w) {
        unsigned long long m = 0;
        for (int k2 = 0; k2 < 64; ++k2) {
            int j = w * 64 + k2;
            float iw = fminf(ri, sr[j]) - fmaxf(li, sl[j]); iw = fmaxf(iw, 0.f);
            float ih = fminf(bi, sb[j]) - fmaxf(ti, st[j]); ih = fmaxf(ih, 0.f);
            float inter = iw * ih;
            float uni = ai + sa[j] - inter + 1e-10f;
            if (inter / uni >= 0.2f) m |= (1ull << k2);
        }
        mask[(size_t)i * 64 + (jc * 4 + w)] = m;
    }
}

// ---------- K7: batched speculative NMS scan, 1 wave, LDS-staged (unchanged) ----------
__global__ __launch_bounds__(64, 1) void k_nms(const unsigned long long* __restrict__ mask,
                                               const float* __restrict__ topv,
                                               const float* __restrict__ area,
                                               unsigned long long* __restrict__ keptW) {
    __shared__ unsigned long long rowsL[2][4096];   // 2 x 32KB: 64 rows x 64 words
    int lane = threadIdx.x;

#define STAGE(bb, s)                                                            \
    do {                                                                        \
        _Pragma("unroll") for (int q = 0; q < 32; ++q) {                        \
            int r_ = (bb) * 64 + q * 2 + (lane >> 5);                           \
            int P_ = (lane & 31) ^ (r_ & 31);                                   \
            const unsigned long long* gp_ = mask + (size_t)r_ * 64 + P_ * 2;    \
            __builtin_amdgcn_global_load_lds(                                   \
                (const __attribute__((address_space(1))) void*)gp_,             \
                (__attribute__((address_space(3))) void*)&rowsL[s][q * 128],    \
                16, 0, 0);                                                      \
        }                                                                       \
    } while (0)

    STAGE(0, 0);
    STAGE(1, 1);

    unsigned long long alive = 0, areaok = 0;
    for (int k = 0; k < 64; ++k) {
        float tv = topv[(size_t)k * 64 + lane];
        float ar = area[(size_t)k * 64 + lane];
        unsigned long long b1 = __ballot(tv != -INFINITY);
        unsigned long long b2 = __ballot(ar >= 4.0f);
        if (lane == k) { alive = b1; areaok = b2; }
    }

    for (int b = 0; b < 64; ++b) {
        if (b < 63) {
            asm volatile("s_waitcnt vmcnt(32)" ::: "memory");
        } else {
            asm volatile("s_waitcnt vmcnt(0)" ::: "memory");
        }
        __builtin_amdgcn_sched_barrier(0);

        const unsigned long long* rb = rowsL[b & 1];
        unsigned long long aw0snap = readlane64(alive, b);
        unsigned long long areaok0 = readlane64(areaok, b);

        int sw = lane & 31;
        unsigned cnt = 0;
#pragma unroll
        for (int P = 0; P < 32; ++P) {
            const ulonglong2 rv = *(const ulonglong2*)&rb[lane * 64 + ((P ^ sw) << 1)];
            unsigned long long a0 = readlane64(alive, 2 * P);
            unsigned long long a1 = readlane64(alive, 2 * P + 1);
            cnt += (unsigned)__popcll(rv.x & a0) + (unsigned)__popcll(rv.y & a1);
        }
        unsigned long long m_w0 = rb[lane * 64 + ((((b >> 1) ^ sw)) << 1) + (b & 1)];
        unsigned long long pfx = (lane == 63) ? ~0ull : ((1ull << (lane + 1)) - 1ull);
        cnt -= (unsigned)__popcll(m_w0 & aw0snap & pfx);

        bool candp = (cnt >= 10u) && ((areaok0 >> lane) & 1ull) && ((aw0snap >> lane) & 1ull);
        unsigned long long cand = __ballot(candp);
        unsigned long long keptB = 0;

        while (cand) {
            int j1 = __ffsll(cand) - 1;
            cand &= cand - 1;
            unsigned long long aw0cur = readlane64(alive, b);
            if (!((aw0cur >> j1) & 1ull)) continue;
            unsigned long long rw = rb[(size_t)j1 * 64 + (((lane >> 1) ^ (j1 & 31)) << 1) + (lane & 1)];
            unsigned long long awAdj = alive;
            unsigned long long pm = (j1 == 63) ? ~0ull : ((1ull << (j1 + 1)) - 1ull);
            if (lane == b) awAdj &= ~pm;
            unsigned c = (unsigned)__popcll(rw & awAdj);
            unsigned tt = wave_sum64_s(c);
            if (tt >= 10u) {
                alive &= ~rw;
                keptB |= 1ull << j1;
            }
        }

        if (lane == b) alive = 0;
        if (lane == 0) keptW[b] = keptB;

        if (b + 2 < 64) { STAGE(b + 2, (b & 1)); }
    }
#undef STAGE
}

// ---------- K8: epilogue ----------
__global__ __launch_bounds__(256) void k_out(const unsigned long long* __restrict__ keptW,
                                             const float* __restrict__ topv,
                                             const float* __restrict__ bl, const float* __restrict__ bt,
                                             const float* __restrict__ br, const float* __restrict__ bb,
                                             const int* __restrict__ clsk,
                                             const float* __restrict__ padding,
                                             const float* __restrict__ ratio,
                                             const int* __restrict__ piw, const int* __restrict__ pih,
                                             float* __restrict__ out) {
    int i = blockIdx.x * 256 + threadIdx.x;
    if (i >= KSEL) return;
    bool kept = (keptW[i >> 6] >> (i & 63)) & 1ull;
    float tv = topv[i];
    bool keep = kept && (tv >= 0.5f);
    float p0 = padding[0], p1 = padding[1];
    float invr = 1.0f / ratio[0];
    float W_ = (float)piw[0], H_ = (float)pih[0];
    float x1 = fmaxf((bl[i] - p0) * invr, 0.f);
    float y1 = fmaxf((bt[i] - p1) * invr, 0.f);
    float x2 = fminf((br[i] - p0) * invr, W_);
    float y2 = fminf((bb[i] - p1) * invr, H_);
    keep = keep && (x1 < W_) && (y1 < H_);
    float* o = out + (size_t)i * 7;
    if (keep) {
        o[0] = 1.0f; o[1] = tv; o[2] = x1; o[3] = y1; o[4] = x2; o[5] = y2;
        o[6] = (float)clsk[i];
    } else {
        o[0] = 0.f; o[1] = 0.f; o[2] = 0.f; o[3] = 0.f; o[4] = 0.f; o[5] = 0.f; o[6] = 0.f;
    }
}

extern "C" void kernel_launch(void* const* d_in, const int* in_sizes, int n_in,
                              void* d_out, int out_size, void* d_ws, size_t ws_size,
                              hipStream_t stream) {
    const float* x       = (const float*)d_in[0];
    const float* sm      = (const float*)d_in[1];
    const float* padding = (const float*)d_in[2];
    const float* ratio   = (const float*)d_in[3];
    const int*   piw     = (const int*)d_in[4];
    const int*   pih     = (const int*)d_in[5];
    float* out = (float*)d_out;
    char* ws = (char*)d_ws;

    // workspace layout (bytes)
    float* score               = (float*)(ws + 0);                 // 409600
    int*   clsidx              = (int*)(ws + 409600);              // 409600
    unsigned* hist             = (unsigned*)(ws + 819200);         // 262144
    unsigned* meta             = (unsigned*)(ws + 1081344);        // 512 (meta[0]=counter, meta[1]=p16)
    unsigned long long* cand   = (unsigned long long*)(ws + 1081856); // CAP*8 = 131072
    float* topv                = (float*)(ws + 1212928);           // 16384
    float* bl                  = (float*)(ws + 1229312);
    float* bt                  = (float*)(ws + 1245696);
    float* br                  = (float*)(ws + 1262080);
    float* bb                  = (float*)(ws + 1278464);
    float* area                = (float*)(ws + 1294848);
    int*   clsk                = (int*)(ws + 1311232);
    unsigned long long* keptW  = (unsigned long long*)(ws + 1327616); // 512
    unsigned long long* mask   = (unsigned long long*)(ws + 1328128); // 2097152

    hipMemsetAsync(hist, 0, 262144 + 512, stream);  // hist + meta

    k_score  <<<400, 256, 0, stream>>>(x, sm, score, clsidx);
    k_hist   <<<400, 256, 0, stream>>>(score, hist);
    k_findp  <<<1, 1024, 0, stream>>>(hist, meta);
    k_collect<<<400, 256, 0, stream>>>(score, meta, cand);
    k_rank   <<<CAP / 256, 256, 0, stream>>>(cand, meta, x, score, clsidx,
                                             topv, bl, bt, br, bb, area, clsk);
    k_mask   <<<256, 256, 0, stream>>>(bl, bt, br, bb, area, mask);
    k_nms    <<<1, 64, 0, stream>>>(mask, topv, area, keptW);
    k_out    <<<16, 256, 0, stream>>>(keptW, topv, bl, bt, br, bb, clsk,
                                      padding, ratio, piw, pih, out);
}

// Round 10
// 324.655 us; speedup vs baseline: 3.7257x; 1.1543x over previous
//
#include <hip/hip_runtime.h>
#include <hip/hip_bf16.h>
#include <math.h>

#define HW 102400        // 320*320
#define KSEL 4096
#define CAP 16384

// ---------- helpers ----------
__device__ inline unsigned fkey(float f) {
    unsigned u = __float_as_uint(f);
    return (u & 0x80000000u) ? ~u : (u | 0x80000000u);
}

// wave64 sum via DPP (row_shr 1/2/4/8 + row_bcast 15/31); result valid in lane 63,
// returned through readlane -> SGPR (wave-uniform, enables scalar branch).
__device__ inline unsigned wave_sum64_s(unsigned x) {
    x += (unsigned)__builtin_amdgcn_update_dpp(0, (int)x, 0x111, 0xf, 0xf, false);
    x += (unsigned)__builtin_amdgcn_update_dpp(0, (int)x, 0x112, 0xf, 0xf, false);
    x += (unsigned)__builtin_amdgcn_update_dpp(0, (int)x, 0x114, 0xf, 0xf, false);
    x += (unsigned)__builtin_amdgcn_update_dpp(0, (int)x, 0x118, 0xf, 0xf, false);
    x += (unsigned)__builtin_amdgcn_update_dpp(0, (int)x, 0x142, 0xa, 0xf, false);
    x += (unsigned)__builtin_amdgcn_update_dpp(0, (int)x, 0x143, 0xc, 0xf, false);
    return (unsigned)__builtin_amdgcn_readlane((int)x, 63);
}

__device__ inline unsigned long long readlane64(unsigned long long v, int l) {
    unsigned lo = (unsigned)__builtin_amdgcn_readlane((int)(unsigned)(v & 0xffffffffull), l);
    unsigned hi = (unsigned)__builtin_amdgcn_readlane((int)(unsigned)(v >> 32), l);
    return ((unsigned long long)hi << 32) | lo;
}

// ---------- K1: score + class argmax (unchanged from r9) ----------
__global__ __launch_bounds__(256) void k_score(const float* __restrict__ x,
                                               const float* __restrict__ sm,
                                               float* __restrict__ score,
                                               int* __restrict__ clsidx) {
    __shared__ float swt[256][16];      // 16KB: swt[c][k] = sm[k*256+c]
    __shared__ float tile[2][16][256];  // 32KB
    int t = threadIdx.x;
    for (int i = t; i < 4096; i += 256) {
        int k = i >> 8, c = i & 255;
        swt[c][k] = sm[i];
    }
    int wave = t >> 6, lane = t & 63;
    size_t pxb = (size_t)blockIdx.x * 256;
    const float* xc = x + (size_t)5 * HW + pxb;

    float acc[16];
#pragma unroll
    for (int k = 0; k < 16; ++k) acc[k] = 0.f;

    float4 sa[4], sb[4];

#define LOADX(dst, ti)                                                         \
    _Pragma("unroll") for (int j = 0; j < 4; ++j)                              \
        dst[j] = *(const float4*)(xc + (size_t)((ti) * 16 + wave * 4 + j) * HW + lane * 4);
#define STOREX(src, s)                                                         \
    _Pragma("unroll") for (int j = 0; j < 4; ++j)                              \
        ((float4*)&tile[s][wave * 4 + j][0])[lane] = src[j];
#define COMP(s, ti)                                                            \
    _Pragma("unroll") for (int cc = 0; cc < 16; ++cc) {                        \
        float xv = tile[s][cc][t];                                             \
        const float4* w4 = (const float4*)&swt[(ti) * 16 + cc][0];             \
        float4 w0 = w4[0], w1 = w4[1], w2 = w4[2], w3 = w4[3];                 \
        acc[0]  = fmaf(xv, w0.x, acc[0]);  acc[1]  = fmaf(xv, w0.y, acc[1]);   \
        acc[2]  = fmaf(xv, w0.z, acc[2]);  acc[3]  = fmaf(xv, w0.w, acc[3]);   \
        acc[4]  = fmaf(xv, w1.x, acc[4]);  acc[5]  = fmaf(xv, w1.y, acc[5]);   \
        acc[6]  = fmaf(xv, w1.z, acc[6]);  acc[7]  = fmaf(xv, w1.w, acc[7]);   \
        acc[8]  = fmaf(xv, w2.x, acc[8]);  acc[9]  = fmaf(xv, w2.y, acc[9]);   \
        acc[10] = fmaf(xv, w2.z, acc[10]); acc[11] = fmaf(xv, w2.w, acc[11]);  \
        acc[12] = fmaf(xv, w3.x, acc[12]); acc[13] = fmaf(xv, w3.y, acc[13]);  \
        acc[14] = fmaf(xv, w3.z, acc[14]); acc[15] = fmaf(xv, w3.w, acc[15]);  \
    }

    LOADX(sa, 0);
    STOREX(sa, 0);
    LOADX(sa, 1);
    LOADX(sb, 2);
    __syncthreads();

#pragma unroll
    for (int k = 0; k < 16; k += 2) {
        COMP(k & 1, k);
        STOREX(sa, (k + 1) & 1);
        if (k + 3 < 16) LOADX(sa, k + 3);
        __syncthreads();
        COMP((k + 1) & 1, k + 1);
        if (k + 2 < 16) { STOREX(sb, k & 1); }
        if (k + 4 < 16) LOADX(sb, k + 4);
        __syncthreads();
    }
#undef LOADX
#undef STOREX
#undef COMP

    float mv = acc[0]; int mi = 0;
#pragma unroll
    for (int k = 1; k < 16; ++k)
        if (acc[k] > mv) { mv = acc[k]; mi = k; }
    int n = (int)pxb + t;
    float x0 = x[n];
    float sig = 1.0f / (1.0f + expf(-x0));
    float sc = (sig > 0.5f) ? sig * mv : -INFINITY;
    score[n] = sc;
    clsidx[n] = mi;
}

// ---------- K2: histogram, VALID (finite) scores only ----------
__global__ void k_hist(const float* __restrict__ score, unsigned* __restrict__ hist) {
    int n = blockIdx.x * 256 + threadIdx.x;
    float sc = score[n];
    if (sc != -INFINITY) atomicAdd(&hist[fkey(sc) >> 16], 1u);
}

// ---------- K3: find 16-bit prefix p16 such that count(key>>16 >= p16) >= K ----------
__global__ __launch_bounds__(1024) void k_findp(const unsigned* __restrict__ hist,
                                                unsigned* __restrict__ meta) {
    __shared__ unsigned part[1024];
    __shared__ unsigned sgrp, s_after;
    __shared__ unsigned bins[64];
    int t = threadIdx.x;
    if (t == 0) { sgrp = 0; s_after = 0; }
    unsigned s = 0;
    const unsigned* hp = hist + t * 64;
    for (int i = 0; i < 64; ++i) s += hp[i];
    part[t] = s;
    __syncthreads();
    for (int off = 1; off < 1024; off <<= 1) {
        unsigned v = (t + off < 1024) ? part[t + off] : 0u;
        __syncthreads();
        part[t] += v;
        __syncthreads();
    }
    if (part[t] >= KSEL && (t == 1023 || part[t + 1] < KSEL)) {
        sgrp = (unsigned)t;
        s_after = (t == 1023) ? 0u : part[t + 1];
    }
    __syncthreads();
    unsigned g = sgrp, SA = s_after;
    if (t < 64) bins[t] = hist[g * 64 + t];
    __syncthreads();
    if (t == 0) {
        unsigned acc = SA, p = g * 64;
        for (int b = 63; b >= 0; --b) {
            acc += bins[b];
            if (acc >= KSEL) { p = g * 64 + (unsigned)b; break; }
        }
        meta[1] = p;
    }
}

// ---------- K4: collect candidates with key>>16 >= p16 ----------
__global__ void k_collect(const float* __restrict__ score,
                          unsigned* __restrict__ meta,
                          unsigned long long* __restrict__ cand) {
    int n = blockIdx.x * 256 + threadIdx.x;
    unsigned key = fkey(score[n]);
    if ((key >> 16) >= meta[1]) {
        unsigned pos = atomicAdd(&meta[0], 1u);
        if (pos < CAP)
            cand[pos] = ((unsigned long long)key << 32) | (unsigned)(~(unsigned)n);
    }
}

// ---------- K5: rank candidates (exact top-k ordering) + gather ----------
__global__ __launch_bounds__(256) void k_rank(const unsigned long long* __restrict__ cand,
                                              const unsigned* __restrict__ meta,
                                              const float* __restrict__ x,
                                              const float* __restrict__ score,
                                              const int* __restrict__ clsidx,
                                              float* __restrict__ topv,
                                              float* __restrict__ bl, float* __restrict__ bt,
                                              float* __restrict__ br, float* __restrict__ bb,
                                              float* __restrict__ area, int* __restrict__ clsk) {
    __shared__ unsigned long long tile[1024];
    int C = (int)meta[0]; if (C > CAP) C = CAP;
    int j = blockIdx.x * 256 + threadIdx.x;
    unsigned long long kj = (j < C) ? cand[j] : 0ull;
    unsigned rank = 0;
    for (int tb = 0; tb < C; tb += 1024) {
        int cnt = min(1024, C - tb);
        __syncthreads();
        for (int u = threadIdx.x; u < cnt; u += 256) tile[u] = cand[tb + u];
        __syncthreads();
        if (j < C)
            for (int u = 0; u < cnt; ++u) rank += (tile[u] > kj) ? 1u : 0u;
    }
    if (j < C && rank < KSEL) {
        unsigned n = ~(unsigned)(kj & 0xFFFFFFFFull);
        float l  = x[(size_t)1 * HW + n];
        float tt = x[(size_t)2 * HW + n];
        float r  = x[(size_t)3 * HW + n];
        float b  = x[(size_t)4 * HW + n];
        topv[rank] = score[n];
        bl[rank] = l; bt[rank] = tt; br[rank] = r; bb[rank] = b;
        area[rank] = (r - l) * (b - tt);
        clsk[rank] = clsidx[n];
    }
}

// ---------- K6: pairwise IoU >= 0.2 bitmask, ROW-MAJOR mask[i][w] ----------
__global__ __launch_bounds__(256) void k_mask(const float* __restrict__ bl, const float* __restrict__ bt,
                                              const float* __restrict__ br, const float* __restrict__ bb,
                                              const float* __restrict__ area,
                                              unsigned long long* __restrict__ mask) {
    __shared__ float sl[256], st[256], sr[256], sb[256], sa[256];
    int t = threadIdx.x;
    int ic = blockIdx.x >> 4;
    int jc = blockIdx.x & 15;
    int i = ic * 256 + t;
    int j0 = jc * 256;
    sl[t] = bl[j0 + t]; st[t] = bt[j0 + t]; sr[t] = br[j0 + t];
    sb[t] = bb[j0 + t]; sa[t] = area[j0 + t];
    __syncthreads();
    float li = bl[i], ti = bt[i], ri = br[i], bi = bb[i], ai = area[i];
#pragma unroll
    for (int w = 0; w < 4; ++w) {
        unsigned long long m = 0;
        for (int k2 = 0; k2 < 64; ++k2) {
            int j = w * 64 + k2;
            float iw = fminf(ri, sr[j]) - fmaxf(li, sl[j]); iw = fmaxf(iw, 0.f);
            float ih = fminf(bi, sb[j]) - fmaxf(ti, st[j]); ih = fmaxf(ih, 0.f);
            float inter = iw * ih;
            float uni = ai + sa[j] - inter + 1e-10f;
            if (inter / uni >= 0.2f) m |= (1ull << k2);
        }
        mask[(size_t)i * 64 + (jc * 4 + w)] = m;
    }
}

// ---------- K7: batched speculative NMS, 4 waves ----------
// Pre-scan (all 256 threads): thread (row j = t>>2, group g = t&3) counts
// popcount over its 16 words using aliveL (LDS mirror of wave-0 alive) ->
// quad DPP reduce -> cntL[j]. Wave 0 alone verifies candidates in order
// (exact distributed count, 4-at-a-time row preloads), updates register alive
// and mirrors to aliveL. Raw s_barrier + explicit waitcnts keep the counted
// vmcnt(8) stage pipeline alive across barriers. LDS row layout swizzled:
// logical word w of row r lives at phys (w + 2r) & 63 (stage source permuted
// to match, rule #21).
__global__ __launch_bounds__(256, 1) void k_nms(const unsigned long long* __restrict__ mask,
                                                const float* __restrict__ topv,
                                                const float* __restrict__ area,
                                                unsigned long long* __restrict__ keptW) {
    __shared__ unsigned long long rowsL[2][4096];   // 2 x 32KB
    __shared__ unsigned long long aliveL[64];
    __shared__ unsigned cntL[64];
    int t = threadIdx.x;
    int lane = t & 63;
    int W = t >> 6;
    int g = t & 3;          // word-group (16 logical words)
    int jrow = t >> 2;      // row in batch 0..63

    // ---- wave 0: init register-distributed alive/areaok; mirror alive to LDS
    unsigned long long alive = 0, areaok = 0, keptAcc = 0;
    if (W == 0) {
        for (int k = 0; k < 64; ++k) {
            float tv = topv[(size_t)k * 64 + lane];
            float ar = area[(size_t)k * 64 + lane];
            unsigned long long b1 = __ballot(tv != -INFINITY);
            unsigned long long b2 = __ballot(ar >= 4.0f);
            if (lane == k) { alive = b1; areaok = b2; }
        }
        aliveL[lane] = alive;
    }

    // ---- stage: 8 issues/wave; LDS dest linear, source pre-swizzled
#define STAGE(bb, s)                                                            \
    do {                                                                        \
        _Pragma("unroll") for (int i = 0; i < 8; ++i) {                         \
            int seg_ = i * 4 + W;                                               \
            int r_ = seg_ * 2 + (lane >> 5);                                    \
            int p_ = (lane & 31) * 2;                                           \
            int wl_ = (p_ - 2 * r_) & 63;                                       \
            const unsigned long long* gp_ =                                     \
                mask + ((size_t)((bb) * 64 + r_) * 64 + wl_);                   \
            __builtin_amdgcn_global_load_lds(                                   \
                (const __attribute__((address_space(1))) void*)gp_,             \
                (__attribute__((address_space(3))) void*)&rowsL[s][seg_ * 128], \
                16, 0, 0);                                                      \
        }                                                                       \
    } while (0)

    STAGE(0, 0);
    STAGE(1, 1);

#define VER(jj, rw)                                                             \
    {                                                                           \
        unsigned long long awc = readlane64(alive, b);                          \
        if ((awc >> (jj)) & 1ull) {                                             \
            unsigned long long awAdj = alive;                                   \
            unsigned long long pm = ((jj) == 63) ? ~0ull                        \
                                                 : ((1ull << ((jj) + 1)) - 1ull); \
            if (lane == b) awAdj &= ~pm;                                        \
            unsigned c_ = (unsigned)__popcll((rw) & awAdj);                     \
            unsigned tt_ = wave_sum64_s(c_);                                    \
            if (tt_ >= 10u) { alive &= ~(rw); keptB |= 1ull << (jj); }          \
        }                                                                       \
    }

    for (int b = 0; b < 64; ++b) {
        if (b < 63) asm volatile("s_waitcnt vmcnt(8)" ::: "memory");
        else        asm volatile("s_waitcnt vmcnt(0)" ::: "memory");
        __builtin_amdgcn_sched_barrier(0);
        __builtin_amdgcn_s_barrier();            // B1: stages + prev aliveL visible

        const unsigned long long* rb = &rowsL[b & 1][0];

        // ---- parallel pre-scan
        unsigned long long pfxj = (jrow == 63) ? ~0ull : ((1ull << (jrow + 1)) - 1ull);
        int base_w = g * 16;
        unsigned cnt = 0;
#pragma unroll
        for (int q = 0; q < 8; ++q) {
            int wl = base_w + q * 2;                       // logical words wl, wl+1
            int ph = (wl + 2 * jrow) & 63;                 // phys (even, pair-contiguous)
            ulonglong2 rv = *(const ulonglong2*)&rb[jrow * 64 + ph];
            ulonglong2 av = *(const ulonglong2*)&aliveL[wl];
            unsigned cx = (unsigned)__popcll(rv.x & av.x);
            unsigned cy = (unsigned)__popcll(rv.y & av.y);
            cnt += cx + cy;
            if (wl == b)     cnt -= (unsigned)__popcll(rv.x & av.x & pfxj);
            if (wl + 1 == b) cnt -= (unsigned)__popcll(rv.y & av.y & pfxj);
        }
        // quad reduce (lanes j*4..j*4+3 same wave): quad_perm swaps
        cnt += (unsigned)__builtin_amdgcn_update_dpp(0, (int)cnt, 0xB1, 0xf, 0xf, false);
        cnt += (unsigned)__builtin_amdgcn_update_dpp(0, (int)cnt, 0x4E, 0xf, 0xf, false);
        if (g == 0) cntL[jrow] = cnt;
        asm volatile("s_waitcnt lgkmcnt(0)" ::: "memory");
        __builtin_amdgcn_s_barrier();            // B2: cntL ready

        // ---- wave 0: ordered exact verification
        if (W == 0) {
            unsigned long long keptB = 0;
            unsigned long long aw0snap = readlane64(alive, b);
            unsigned long long areaok0 = readlane64(areaok, b);
            unsigned myc = cntL[lane];
            bool candp = (myc >= 10u) && ((areaok0 >> lane) & 1ull) &&
                         ((aw0snap >> lane) & 1ull);
            unsigned long long cand = __ballot(candp);
            while (cand) {
                int j1 = __ffsll(cand) - 1; cand &= cand - 1;
                int j2 = -1, j3 = -1, j4 = -1;
                if (cand) { j2 = __ffsll(cand) - 1; cand &= cand - 1; }
                if (cand) { j3 = __ffsll(cand) - 1; cand &= cand - 1; }
                if (cand) { j4 = __ffsll(cand) - 1; cand &= cand - 1; }
                // preload candidate rows (data static; pipelined ds_reads)
                unsigned long long r1 = rb[j1 * 64 + ((lane + 2 * j1) & 63)];
                unsigned long long r2 = (j2 >= 0) ? rb[j2 * 64 + ((lane + 2 * j2) & 63)] : 0;
                unsigned long long r3 = (j3 >= 0) ? rb[j3 * 64 + ((lane + 2 * j3) & 63)] : 0;
                unsigned long long r4 = (j4 >= 0) ? rb[j4 * 64 + ((lane + 2 * j4) & 63)] : 0;
                VER(j1, r1);
                if (j2 >= 0) VER(j2, r2);
                if (j3 >= 0) VER(j3, r3);
                if (j4 >= 0) VER(j4, r4);
            }
            if (lane == b) { alive = 0; keptAcc = keptB; }
            aliveL[lane] = alive;
        }
        asm volatile("s_waitcnt lgkmcnt(0)" ::: "memory");
        __builtin_amdgcn_s_barrier();            // B3: aliveL ready; rowsL[cur] free
        if (b + 2 < 64) STAGE(b + 2, b & 1);
    }
    if (W == 0) keptW[lane] = keptAcc;
#undef STAGE
#undef VER
}

// ---------- K8: epilogue ----------
__global__ __launch_bounds__(256) void k_out(const unsigned long long* __restrict__ keptW,
                                             const float* __restrict__ topv,
                                             const float* __restrict__ bl, const float* __restrict__ bt,
                                             const float* __restrict__ br, const float* __restrict__ bb,
                                             const int* __restrict__ clsk,
                                             const float* __restrict__ padding,
                                             const float* __restrict__ ratio,
                                             const int* __restrict__ piw, const int* __restrict__ pih,
                                             float* __restrict__ out) {
    int i = blockIdx.x * 256 + threadIdx.x;
    if (i >= KSEL) return;
    bool kept = (keptW[i >> 6] >> (i & 63)) & 1ull;
    float tv = topv[i];
    bool keep = kept && (tv >= 0.5f);
    float p0 = padding[0], p1 = padding[1];
    float invr = 1.0f / ratio[0];
    float W_ = (float)piw[0], H_ = (float)pih[0];
    float x1 = fmaxf((bl[i] - p0) * invr, 0.f);
    float y1 = fmaxf((bt[i] - p1) * invr, 0.f);
    float x2 = fminf((br[i] - p0) * invr, W_);
    float y2 = fminf((bb[i] - p1) * invr, H_);
    keep = keep && (x1 < W_) && (y1 < H_);
    float* o = out + (size_t)i * 7;
    if (keep) {
        o[0] = 1.0f; o[1] = tv; o[2] = x1; o[3] = y1; o[4] = x2; o[5] = y2;
        o[6] = (float)clsk[i];
    } else {
        o[0] = 0.f; o[1] = 0.f; o[2] = 0.f; o[3] = 0.f; o[4] = 0.f; o[5] = 0.f; o[6] = 0.f;
    }
}

extern "C" void kernel_launch(void* const* d_in, const int* in_sizes, int n_in,
                              void* d_out, int out_size, void* d_ws, size_t ws_size,
                              hipStream_t stream) {
    const float* x       = (const float*)d_in[0];
    const float* sm      = (const float*)d_in[1];
    const float* padding = (const float*)d_in[2];
    const float* ratio   = (const float*)d_in[3];
    const int*   piw     = (const int*)d_in[4];
    const int*   pih     = (const int*)d_in[5];
    float* out = (float*)d_out;
    char* ws = (char*)d_ws;

    // workspace layout (bytes)
    float* score               = (float*)(ws + 0);                 // 409600
    int*   clsidx              = (int*)(ws + 409600);              // 409600
    unsigned* hist             = (unsigned*)(ws + 819200);         // 262144
    unsigned* meta             = (unsigned*)(ws + 1081344);        // 512 (meta[0]=counter, meta[1]=p16)
    unsigned long long* cand   = (unsigned long long*)(ws + 1081856); // CAP*8 = 131072
    float* topv                = (float*)(ws + 1212928);           // 16384
    float* bl                  = (float*)(ws + 1229312);
    float* bt                  = (float*)(ws + 1245696);
    float* br                  = (float*)(ws + 1262080);
    float* bb                  = (float*)(ws + 1278464);
    float* area                = (float*)(ws + 1294848);
    int*   clsk                = (int*)(ws + 1311232);
    unsigned long long* keptW  = (unsigned long long*)(ws + 1327616); // 512
    unsigned long long* mask   = (unsigned long long*)(ws + 1328128); // 2097152

    hipMemsetAsync(hist, 0, 262144 + 512, stream);  // hist + meta

    k_score  <<<400, 256, 0, stream>>>(x, sm, score, clsidx);
    k_hist   <<<400, 256, 0, stream>>>(score, hist);
    k_findp  <<<1, 1024, 0, stream>>>(hist, meta);
    k_collect<<<400, 256, 0, stream>>>(score, meta, cand);
    k_rank   <<<CAP / 256, 256, 0, stream>>>(cand, meta, x, score, clsidx,
                                             topv, bl, bt, br, bb, area, clsk);
    k_mask   <<<256, 256, 0, stream>>>(bl, bt, br, bb, area, mask);
    k_nms    <<<1, 256, 0, stream>>>(mask, topv, area, keptW);
    k_out    <<<16, 256, 0, stream>>>(keptW, topv, bl, bt, br, bb, clsk,
                                      padding, ratio, piw, pih, out);
}